// Round 21
// baseline (190.689 us; speedup 1.0000x reference)
//
#include <hip/hip_runtime.h>
#include <hip/hip_bf16.h>

// ---------------------------------------------------------------------------
// Fused GQA attention block: out = dense( attn( x*Wq, x*Wkv ) )
// B=2, SQ=2048, HIDDEN=2048, HEADS=16, GROUPS=4, KVC=128, causal, scale=1/sqrt(128)
// R21: attn v15 — v7's verified body (KBLK=64 single-buffer, 40KB -> 4
//      blocks/CU, 1024 blocks) + v13's BALANCED qt bijection: CU c's four
//      blocks get qt in {s, 63-s, 64+s, 127-s} -> uniform 67.5 phases/CU
//      (v7's long-first map spread 53..84).  GEMMs/preps frozen from R20.
// ---------------------------------------------------------------------------

typedef __attribute__((ext_vector_type(4))) float f32x4;
typedef __attribute__((ext_vector_type(8))) short bf16x8;
typedef __attribute__((ext_vector_type(4))) short bf16x4;

__device__ __forceinline__ unsigned short f2bf(float f) {
    unsigned u = __builtin_bit_cast(unsigned, f);
    unsigned r = u + 0x7fffu + ((u >> 16) & 1u);   // round-to-nearest-even
    return (unsigned short)(r >> 16);
}

__device__ __forceinline__ unsigned cvtpk_bf16(float lo, float hi) {
    unsigned r;
    asm("v_cvt_pk_bf16_f32 %0, %1, %2" : "=v"(r) : "v"(lo), "v"(hi));
    return r;
}

// async global->LDS, 16B/lane; LDS dest = wave-uniform base + lane*16
__device__ __forceinline__ void gl_lds16(const void* g, void* l) {
    __builtin_amdgcn_global_load_lds(
        (const __attribute__((address_space(1))) unsigned int*)g,
        (__attribute__((address_space(3))) unsigned int*)l, 16, 0, 0);
}

// XCD-aware bijective remap (requires nwg % 8 == 0)
__device__ __forceinline__ int xcd_swizzle(int lin, int nwg) {
    return (lin & 7) * (nwg >> 3) + (lin >> 3);
}

// ---------------------------------------------------------------------------
// Fused prep bodies
// ---------------------------------------------------------------------------
__device__ __forceinline__ void xcvt_body(const float* __restrict__ in,
                                          unsigned short* __restrict__ out,
                                          int blk)
{
    size_t i = ((size_t)blk * 256 + threadIdx.x) * 8;
    float4 a = *reinterpret_cast<const float4*>(&in[i]);
    float4 b = *reinterpret_cast<const float4*>(&in[i + 4]);
    bf16x8 o = { (short)f2bf(a.x), (short)f2bf(a.y),
                 (short)f2bf(a.z), (short)f2bf(a.w),
                 (short)f2bf(b.x), (short)f2bf(b.y),
                 (short)f2bf(b.z), (short)f2bf(b.w) };
    *reinterpret_cast<bf16x8*>(&out[i]) = o;
}

// fp32 [K][N] -> bf16 [N][K], one 64x64 tile; T is 64x72 shared scratch
__device__ __forceinline__ void wtrans_body(const float* __restrict__ in,
                                            unsigned short* __restrict__ out,
                                            int K, int N, int bx, int by,
                                            unsigned short* T)
{
    const int n0 = bx * 64, k0 = by * 64;
    const int tid = threadIdx.x;
#pragma unroll
    for (int i = 0; i < 4; ++i) {
        int f = tid + i * 256;
        int r = f >> 4;
        int c4 = (f & 15) * 4;
        float4 v = *reinterpret_cast<const float4*>(&in[(size_t)(k0 + r) * N + n0 + c4]);
        bf16x4 pk = { (short)f2bf(v.x), (short)f2bf(v.y),
                      (short)f2bf(v.z), (short)f2bf(v.w) };
        *reinterpret_cast<bf16x4*>(&T[r * 72 + c4]) = pk;
    }
    __syncthreads();
#pragma unroll
    for (int i = 0; i < 2; ++i) {
        int f = tid + i * 256;
        int nn = f >> 3;
        int s8 = (f & 7) * 8;
        bf16x8 o;
#pragma unroll
        for (int j = 0; j < 8; ++j) o[j] = T[(s8 + j) * 72 + nn];
        *reinterpret_cast<bf16x8*>(&out[(size_t)(n0 + nn) * K + k0 + s8]) = o;
    }
}

// kv v-part [b][s][512+g*128+d] -> vt [b*4+g][d][s], one 64-seq tile
__device__ __forceinline__ void vtrans_body(const unsigned short* __restrict__ kv,
                                            unsigned short* __restrict__ vt,
                                            int bx, int bg, unsigned short* T)
{
    const int b = bg >> 2, g = bg & 3;
    const int s0 = bx * 64;
    const int tid = threadIdx.x;
#pragma unroll
    for (int i = 0; i < 4; ++i) {
        int f = tid + i * 256;
        int sl = f >> 4;
        int d0 = (f & 15) * 8;
        bf16x8 v = *reinterpret_cast<const bf16x8*>(
            &kv[(size_t)(b * 2048 + s0 + sl) * 1024 + 512 + g * 128 + d0]);
        bf16x4 lo = { v[0], v[1], v[2], v[3] };
        bf16x4 hi = { v[4], v[5], v[6], v[7] };
        *reinterpret_cast<bf16x4*>(&T[sl * 140 + d0])     = lo;
        *reinterpret_cast<bf16x4*>(&T[sl * 140 + d0 + 4]) = hi;
    }
    __syncthreads();
#pragma unroll
    for (int i = 0; i < 4; ++i) {
        int f = tid + i * 256;
        int d = f >> 3;
        int s8 = (f & 7) * 8;
        bf16x8 o;
#pragma unroll
        for (int j = 0; j < 8; ++j) o[j] = T[(s8 + j) * 140 + d];
        *reinterpret_cast<bf16x8*>(
            &vt[(size_t)(bg * 128 + d) * 2048 + s0 + s8]) = o;
    }
}

// prep1: xcvt (4096) | wtrans wq (1024) | wtrans wkv (512)  = 5632 blocks
__global__ __launch_bounds__(256)
void prep1_kernel(const float* __restrict__ x, unsigned short* __restrict__ xbf,
                  const float* __restrict__ w_q, unsigned short* __restrict__ wqT,
                  const float* __restrict__ w_kv, unsigned short* __restrict__ wkvT)
{
    __shared__ __align__(16) unsigned short T[64 * 72];
    const int bid = blockIdx.x;
    if (bid < 4096) {
        xcvt_body(x, xbf, bid);
    } else if (bid < 4096 + 1024) {
        int r = bid - 4096;
        wtrans_body(w_q, wqT, 2048, 2048, r & 31, r >> 5, T);
    } else {
        int r = bid - 5120;
        wtrans_body(w_kv, wkvT, 2048, 1024, r & 15, r >> 4, T);
    }
}

// prep2: wtrans wdense (1024) | vtrans (256)  = 1280 blocks
__global__ __launch_bounds__(256)
void prep2_kernel(const float* __restrict__ w_dense, unsigned short* __restrict__ wdT,
                  const unsigned short* __restrict__ kv, unsigned short* __restrict__ vt)
{
    __shared__ __align__(16) unsigned short T[64 * 140];
    const int bid = blockIdx.x;
    if (bid < 1024) {
        wtrans_body(w_dense, wdT, 2048, 2048, bid & 31, bid >> 5, T);
    } else {
        int r = bid - 1024;
        vtrans_body(kv, vt, r & 31, r >> 5, T);
    }
}

// ---------------------------------------------------------------------------
// qkv GEMM: BK=32 triple-buffer, depth-2 prefetch, vmcnt(8), XCD swizzle.
// Epilogue: q cols scaled by scale*log2(e); kv cols to C1.  (frozen R19)
// ---------------------------------------------------------------------------
__global__ __launch_bounds__(256)
void gemm_qkv_kernel(const unsigned short* __restrict__ A,
                     const unsigned short* __restrict__ BT,
                     void* __restrict__ C0v, void* __restrict__ C1v,
                     int M, int N, int K)
{
    __shared__ __align__(16) unsigned short Alds[3][128 * 32];   // 3 x 8KB
    __shared__ __align__(16) unsigned short Blds[3][128 * 32];   // 3 x 8KB

    const int tid = threadIdx.x;
    const int lane = tid & 63;
    const int wid = tid >> 6;
    const int wr = wid >> 1, wc = wid & 1;
    const int nbx = gridDim.x;
    const int lin = blockIdx.y * nbx + blockIdx.x;
    const int sl = xcd_swizzle(lin, nbx * gridDim.y);
    const int m0 = (sl / nbx) * 128;
    const int n0 = (sl % nbx) * 128;
    const int l16 = lane & 15, lg = lane >> 4;

    f32x4 acc[4][4];
#pragma unroll
    for (int m = 0; m < 4; ++m)
#pragma unroll
        for (int n = 0; n < 4; ++n) acc[m][n] = (f32x4){0.f, 0.f, 0.f, 0.f};

    int srow[2], skb[2];
#pragma unroll
    for (int i = 0; i < 2; ++i) {
        int L = i * 4096 + tid * 16;
        int R = L >> 7, c = L & 127;
        int cp = c ^ ((R & 7) << 4);
        srow[i] = 2 * R + (cp >> 6);
        skb[i]  = cp & 63;
    }

    auto stage = [&](int kt, int bi) {
#pragma unroll
        for (int i = 0; i < 2; ++i) {
            int L = i * 4096 + tid * 16;
            gl_lds16((const char*)A + ((size_t)(m0 + srow[i]) * K + kt) * 2 + skb[i],
                     (char*)(&Alds[bi][0]) + L);
            gl_lds16((const char*)BT + ((size_t)(n0 + srow[i]) * K + kt) * 2 + skb[i],
                     (char*)(&Blds[bi][0]) + L);
        }
    };

    const int NK = K / 32;
    stage(0, 0);
    stage(32, 1);

    for (int t = 0; t < NK; ++t) {
        const int bi = t % 3;
        if (t + 2 < NK) {
            stage((t + 2) * 32, (t + 2) % 3);           // depth-2 prefetch
            asm volatile("s_waitcnt vmcnt(8)" ::: "memory");   // tile t landed
        } else if (t + 1 < NK) {
            asm volatile("s_waitcnt vmcnt(4)" ::: "memory");
        } else {
            asm volatile("s_waitcnt vmcnt(0)" ::: "memory");
        }
        __builtin_amdgcn_s_barrier();

        const char* Ab = (const char*)(&Alds[bi][0]);
        const char* Bb = (const char*)(&Blds[bi][0]);

        bf16x8 af[4], bf[4];
#pragma unroll
        for (int m = 0; m < 4; ++m) {
            int row = wr * 64 + m * 16 + l16;
            int byte = (row >> 1) * 128 +
                       ((((row & 1) << 6) + lg * 16) ^ (((row >> 1) & 7) << 4));
            af[m] = *reinterpret_cast<const bf16x8*>(Ab + byte);
        }
#pragma unroll
        for (int n = 0; n < 4; ++n) {
            int row = wc * 64 + n * 16 + l16;
            int byte = (row >> 1) * 128 +
                       ((((row & 1) << 6) + lg * 16) ^ (((row >> 1) & 7) << 4));
            bf[n] = *reinterpret_cast<const bf16x8*>(Bb + byte);
        }
#pragma unroll
        for (int m = 0; m < 4; ++m)
#pragma unroll
            for (int n = 0; n < 4; ++n)
                acc[m][n] = __builtin_amdgcn_mfma_f32_16x16x32_bf16(
                    af[m], bf[n], acc[m][n], 0, 0, 0);

        __builtin_amdgcn_s_barrier();   // all reads of buf[bi] done before
    }                                   // it is restaged at t+3

#pragma unroll
    for (int m = 0; m < 4; ++m) {
#pragma unroll
        for (int n = 0; n < 4; ++n) {
#pragma unroll
            for (int r = 0; r < 4; ++r) {
                int row = m0 + wr * 64 + m * 16 + lg * 4 + r;
                int col = n0 + wc * 64 + n * 16 + l16;
                float val = acc[m][n][r];
                if (n0 < 2048)   // q: fold scale * log2(e) for exp2 softmax
                    ((unsigned short*)C0v)[(size_t)row * 2048 + col] =
                        f2bf(val * 0.12751879523209208f);
                else
                    ((unsigned short*)C1v)[(size_t)row * 1024 + (col - 2048)] = f2bf(val);
            }
        }
    }
}

// ---------------------------------------------------------------------------
// Dense GEMM: BK=64 dbuf + XCD swizzle.  fp32 out.  (frozen R19)
// ---------------------------------------------------------------------------
__global__ __launch_bounds__(256)
void gemm_dense_kernel(const unsigned short* __restrict__ A,
                       const unsigned short* __restrict__ BT,
                       float* __restrict__ C, int M, int N, int K)
{
    __shared__ __align__(16) unsigned short Alds[2][128 * 64];
    __shared__ __align__(16) unsigned short Blds[2][128 * 64];

    const int tid = threadIdx.x;
    const int lane = tid & 63;
    const int wid = tid >> 6;
    const int wr = wid >> 1, wc = wid & 1;
    const int nbx = gridDim.x;
    const int lin = blockIdx.y * nbx + blockIdx.x;
    const int sl = xcd_swizzle(lin, nbx * gridDim.y);
    const int m0 = (sl / nbx) * 128;
    const int n0 = (sl % nbx) * 128;
    const int l16 = lane & 15, lg = lane >> 4;

    f32x4 acc[4][4];
#pragma unroll
    for (int m = 0; m < 4; ++m)
#pragma unroll
        for (int n = 0; n < 4; ++n) acc[m][n] = (f32x4){0.f, 0.f, 0.f, 0.f};

    auto stage = [&](int kt, int bi) {
#pragma unroll
        for (int i = 0; i < 4; ++i) {
            int row = i * 32 + (tid >> 3);
            int cb = ((tid & 7) * 16) ^ ((row & 7) << 4);
            gl_lds16((const char*)A + ((size_t)(m0 + row) * K + kt) * 2 + cb,
                     (char*)(&Alds[bi][0]) + i * 4096 + wid * 1024);
            gl_lds16((const char*)BT + ((size_t)(n0 + row) * K + kt) * 2 + cb,
                     (char*)(&Blds[bi][0]) + i * 4096 + wid * 1024);
        }
    };

    const int NK = K / 64;
    stage(0, 0);
    int cur = 0;

    for (int kti = 0; kti < NK; ++kti) {
        if (kti + 1 < NK) {
            stage((kti + 1) * 64, cur ^ 1);
            asm volatile("s_waitcnt vmcnt(8)" ::: "memory");
        } else {
            asm volatile("s_waitcnt vmcnt(0)" ::: "memory");
        }
        __builtin_amdgcn_s_barrier();

        const char* Ab = (const char*)(&Alds[cur][0]);
        const char* Bb = (const char*)(&Blds[cur][0]);

        bf16x8 af[2][4], bf[2][4];
#pragma unroll
        for (int kd = 0; kd < 2; ++kd) {
#pragma unroll
            for (int m = 0; m < 4; ++m) {
                int row = wr * 64 + m * 16 + l16;
                af[kd][m] = *reinterpret_cast<const bf16x8*>(
                    Ab + row * 128 + ((kd * 64 + lg * 16) ^ ((row & 7) << 4)));
            }
#pragma unroll
            for (int n = 0; n < 4; ++n) {
                int row = wc * 64 + n * 16 + l16;
                bf[kd][n] = *reinterpret_cast<const bf16x8*>(
                    Bb + row * 128 + ((kd * 64 + lg * 16) ^ ((row & 7) << 4)));
            }
        }
#pragma unroll
        for (int kd = 0; kd < 2; ++kd)
#pragma unroll
            for (int m = 0; m < 4; ++m)
#pragma unroll
                for (int n = 0; n < 4; ++n)
                    acc[m][n] = __builtin_amdgcn_mfma_f32_16x16x32_bf16(
                        af[kd][m], bf[kd][n], acc[m][n], 0, 0, 0);

        __builtin_amdgcn_s_barrier();
        cur ^= 1;
    }

#pragma unroll
    for (int m = 0; m < 4; ++m) {
#pragma unroll
        for (int n = 0; n < 4; ++n) {
#pragma unroll
            for (int r = 0; r < 4; ++r) {
                int row = m0 + wr * 64 + m * 16 + lg * 4 + r;
                int col = n0 + wc * 64 + n * 16 + l16;
                C[(size_t)row * N + col] = acc[m][n][r];
            }
        }
    }
}

// ---------------------------------------------------------------------------
// Flash attention v15: v7 body + balanced qt map.  16-row q-tiles, 1024
// blocks (4/CU exact fill via __launch_bounds__(256,4)), 4 waves (1 head
// each), single-buffered K/V (KBLK=64), LDS = 16+16+8 = 40KB.
// Balanced bijection: CU c's four blocks (j = s, s+32, s+64, s+96) get
// qt in {s, 63-s, 64+s, 127-s} -> uniform ~67.5 phases per CU.
// Swapped S^T, exp2-direct softmax (scale pre-folded in q), swizzled P.
// ---------------------------------------------------------------------------
__global__ __launch_bounds__(256, 4)
void attn_kernel(const unsigned short* __restrict__ Q,   // [b][s][h*128+d] (q pre-scaled)
                 const unsigned short* __restrict__ KV,  // [b][s][1024] (k at g*128)
                 const unsigned short* __restrict__ VT,  // [b*4+g][d][s]
                 unsigned short* __restrict__ CTX)       // [b][s][h*128+d]
{
    constexpr int SQ = 2048;
    __shared__ __align__(16) unsigned short Klds[64 * 128];   // 16KB
    __shared__ __align__(16) unsigned short Vlds[128 * 64];   // 16KB
    __shared__ __align__(16) unsigned short Pl[4][16][64];    //  8KB

    const int tid = threadIdx.x;
    const int lane = tid & 63;
    const int w = tid >> 6;                     // 0..3 = head within group
    const int l16 = lane & 15, lg = lane >> 4;

    const int bid = blockIdx.x;
    const int gb = bid & 7;                     // XCD pin
    const int g = gb & 3, b = gb >> 2;
    const int j = bid >> 3;                     // 0..127
    // balanced bijection (uniform per-CU phase sum):
    const int qt = (j < 32) ? j : (j < 64) ? (95 - j) : (j < 96) ? j : (223 - j);
    const int hh = g * 4 + w;

    const size_t qbase = (size_t)b * SQ * 2048;
    const char* KVb = (const char*)KV + (size_t)b * SQ * 2048;  // bytes
    const char* VTb = (const char*)VT;

    bf16x8 qfrag[4];
#pragma unroll
    for (int kd = 0; kd < 4; ++kd)
        qfrag[kd] = *reinterpret_cast<const bf16x8*>(
            &Q[qbase + (size_t)(qt * 16 + l16) * 2048 + hh * 128 + kd * 32 + lg * 8]);

    float lsum = 0.f;
    f32x4 acc[8];
#pragma unroll
    for (int nd = 0; nd < 8; ++nd) acc[nd] = (f32x4){0.f,0.f,0.f,0.f};

    const int ntiles = qt / 4 + 1;
    const int pswz = (l16 & 7) << 3;            // P key-swizzle for this lane

    for (int t = 0; t < ntiles; ++t) {
        const int k0 = t * 64;
        // ---- stage K (64x128) + V^T (128x64), pre-swizzled source ----
#pragma unroll
        for (int i = 0; i < 4; ++i) {
            int row = w * 16 + i * 4 + (lane >> 4);
            int scol = ((lane & 15) * 16) ^ ((row & 7) << 4);
            gl_lds16(KVb + (size_t)(k0 + row) * 2048 + g * 256 + scol,
                     (char*)Klds + w * 4096 + i * 1024);
        }
#pragma unroll
        for (int i = 0; i < 4; ++i) {
            int row = w * 32 + i * 8 + (lane >> 3);
            int scol = ((lane & 7) * 16) ^ ((row & 7) << 4);
            gl_lds16(VTb + ((size_t)(gb * 128 + row) * 2048 + k0) * 2 + scol,
                     (char*)Vlds + w * 4096 + i * 1024);
        }
        __syncthreads();    // drains vmcnt(0): tile staged

        // ---- S^T = K Q^T (swapped operands); q pre-scaled ----
        f32x4 st[4];
#pragma unroll
        for (int nf = 0; nf < 4; ++nf) st[nf] = (f32x4){0.f,0.f,0.f,0.f};
        __builtin_amdgcn_s_setprio(1);
#pragma unroll
        for (int nf = 0; nf < 4; ++nf) {
            int row = nf * 16 + l16;                    // key row
#pragma unroll
            for (int kd = 0; kd < 4; ++kd) {
                bf16x8 kf = *reinterpret_cast<const bf16x8*>(
                    (const char*)Klds + row * 256 +
                    ((kd * 64 + lg * 16) ^ ((row & 7) << 4)));
                st[nf] = __builtin_amdgcn_mfma_f32_16x16x32_bf16(
                    kf, qfrag[kd], st[nf], 0, 0, 0);
            }
        }
        __builtin_amdgcn_s_setprio(0);

        // ---- softmax (exp2 direct, no max), pack P -> LDS ----
        const bool diag = (t == ntiles - 1);
        {
            float lacc = 0.f;
            const int q = qt * 16 + l16;
#pragma unroll
            for (int nf = 0; nf < 4; ++nf) {
                float cs0 = st[nf][0];
                float cs1 = st[nf][1];
                float cs2 = st[nf][2];
                float cs3 = st[nf][3];
                if (diag) {
                    const int keyb = k0 + nf * 16 + lg * 4;
                    if (keyb + 0 > q) cs0 = -INFINITY;
                    if (keyb + 1 > q) cs1 = -INFINITY;
                    if (keyb + 2 > q) cs2 = -INFINITY;
                    if (keyb + 3 > q) cs3 = -INFINITY;
                }
                float p0 = exp2f(cs0), p1 = exp2f(cs1);
                float p2 = exp2f(cs2), p3 = exp2f(cs3);
                lacc += (p0 + p1) + (p2 + p3);
                uint2 pk = { cvtpk_bf16(p0, p1), cvtpk_bf16(p2, p3) };
                *reinterpret_cast<uint2*>(
                    &Pl[w][l16][(nf * 16 + lg * 4) ^ pswz]) = pk;
            }
            lacc += __shfl_xor(lacc, 16, 64);
            lacc += __shfl_xor(lacc, 32, 64);
            lsum += lacc;
        }

        // ---- ctx^T += V^T P^T ----
        __builtin_amdgcn_s_setprio(1);
#pragma unroll
        for (int kc = 0; kc < 2; ++kc) {
            bf16x8 pf = *reinterpret_cast<const bf16x8*>(
                &Pl[w][l16][(kc * 32 + lg * 8) ^ pswz]);
#pragma unroll
            for (int nd = 0; nd < 8; ++nd) {
                int row = nd * 16 + l16;                // d row of V^T
                bf16x8 vf = *reinterpret_cast<const bf16x8*>(
                    (const char*)Vlds + row * 128 +
                    ((kc * 64 + lg * 16) ^ ((row & 7) << 4)));
                acc[nd] = __builtin_amdgcn_mfma_f32_16x16x32_bf16(
                    vf, pf, acc[nd], 0, 0, 0);
            }
        }
        __builtin_amdgcn_s_setprio(0);
        __syncthreads();    // all reads done before next tile restages
    }

    // ---- epilogue: acc = ctx^T (col=q, row=d); lane writes 4 consecutive d ----
    {
        float inv = 1.0f / lsum;
        const int q = qt * 16 + l16;
#pragma unroll
        for (int nd = 0; nd < 8; ++nd) {
            bf16x4 o = { (short)f2bf(acc[nd][0] * inv),
                         (short)f2bf(acc[nd][1] * inv),
                         (short)f2bf(acc[nd][2] * inv),
                         (short)f2bf(acc[nd][3] * inv) };
            *reinterpret_cast<bf16x4*>(
                &CTX[qbase + (size_t)q * 2048 + hh * 128 + nd * 16 + lg * 4]) = o;
        }
    }
}

// ---------------------------------------------------------------------------
extern "C" void kernel_launch(void* const* d_in, const int* in_sizes, int n_in,
                              void* d_out, int out_size, void* d_ws, size_t ws_size,
                              hipStream_t stream)
{
    const float* x       = (const float*)d_in[0];
    const float* w_q     = (const float*)d_in[1];
    const float* w_kv    = (const float*)d_in[2];
    const float* w_dense = (const float*)d_in[3];

    const int M = 4096;                            // B*SQ

    // ws (36 MB): kv 8 @0 | ctx 16 @8 | wqT 8 @24 (reused as wdT) | wkvT 4 @32
    char* ws = (char*)d_ws;
    unsigned short* kv_buf  = (unsigned short*)(ws);
    unsigned short* ctx_buf = (unsigned short*)(ws + (8u << 20));
    unsigned short* wqT     = (unsigned short*)(ws + (24u << 20));
    unsigned short* wkvT    = (unsigned short*)(ws + (32u << 20));
    unsigned short* wdT     = wqT;
    // d_out (32 MB): xbf [0:16M] (dead after qkv GEMM) | q_buf [16:32M];
    // vt [0:4M] reuses xbf's region; dense GEMM finally overwrites all of d_out.
    unsigned short* xbf    = (unsigned short*)d_out;
    unsigned short* q_buf  = (unsigned short*)d_out + (size_t)M * 2048;
    unsigned short* vt_buf = (unsigned short*)d_out;

    dim3 blk(256);
    prep1_kernel<<<dim3(5632), blk, 0, stream>>>(x, xbf, w_q, wqT, w_kv, wkvT);
    gemm_qkv_kernel<<<dim3(24, 32), blk, 0, stream>>>(
        xbf, wqT, (void*)q_buf, (void*)kv_buf, M, 3072, 2048);
    prep2_kernel<<<dim3(1280), blk, 0, stream>>>(w_dense, wdT, kv_buf, vt_buf);
    attn_kernel<<<dim3(1024), blk, 0, stream>>>(q_buf, kv_buf, vt_buf, ctx_buf);
    gemm_dense_kernel<<<dim3(16, 32), blk, 0, stream>>>(
        ctx_buf, wdT, (float*)d_out, M, 2048, 2048);
}

// Round 22
// 183.184 us; speedup vs baseline: 1.0410x; 1.0410x over previous
//
#include <hip/hip_runtime.h>
#include <hip/hip_bf16.h>

// ---------------------------------------------------------------------------
// Fused GQA attention block: out = dense( attn( x*Wq, x*Wkv ) )
// B=2, SQ=2048, HIDDEN=2048, HEADS=16, GROUPS=4, KVC=128, causal, scale=1/sqrt(128)
// R22: revert to the best measured configuration (R19, 183.4us):
//      attn v10 (72.4us) + fused preps + XCD-swizzled GEMMs
//      (qkv BK=32 triple-buffer, dense BK=64 double-buffer).
// ---------------------------------------------------------------------------

typedef __attribute__((ext_vector_type(4))) float f32x4;
typedef __attribute__((ext_vector_type(8))) short bf16x8;
typedef __attribute__((ext_vector_type(4))) short bf16x4;

__device__ __forceinline__ unsigned short f2bf(float f) {
    unsigned u = __builtin_bit_cast(unsigned, f);
    unsigned r = u + 0x7fffu + ((u >> 16) & 1u);   // round-to-nearest-even
    return (unsigned short)(r >> 16);
}

__device__ __forceinline__ unsigned cvtpk_bf16(float lo, float hi) {
    unsigned r;
    asm("v_cvt_pk_bf16_f32 %0, %1, %2" : "=v"(r) : "v"(lo), "v"(hi));
    return r;
}

// async global->LDS, 16B/lane; LDS dest = wave-uniform base + lane*16
__device__ __forceinline__ void gl_lds16(const void* g, void* l) {
    __builtin_amdgcn_global_load_lds(
        (const __attribute__((address_space(1))) unsigned int*)g,
        (__attribute__((address_space(3))) unsigned int*)l, 16, 0, 0);
}

// XCD-aware bijective remap (requires nwg % 8 == 0)
__device__ __forceinline__ int xcd_swizzle(int lin, int nwg) {
    return (lin & 7) * (nwg >> 3) + (lin >> 3);
}

// ---------------------------------------------------------------------------
// Fused prep bodies
// ---------------------------------------------------------------------------
__device__ __forceinline__ void xcvt_body(const float* __restrict__ in,
                                          unsigned short* __restrict__ out,
                                          int blk)
{
    size_t i = ((size_t)blk * 256 + threadIdx.x) * 8;
    float4 a = *reinterpret_cast<const float4*>(&in[i]);
    float4 b = *reinterpret_cast<const float4*>(&in[i + 4]);
    bf16x8 o = { (short)f2bf(a.x), (short)f2bf(a.y),
                 (short)f2bf(a.z), (short)f2bf(a.w),
                 (short)f2bf(b.x), (short)f2bf(b.y),
                 (short)f2bf(b.z), (short)f2bf(b.w) };
    *reinterpret_cast<bf16x8*>(&out[i]) = o;
}

// fp32 [K][N] -> bf16 [N][K], one 64x64 tile; T is 64x72 shared scratch
__device__ __forceinline__ void wtrans_body(const float* __restrict__ in,
                                            unsigned short* __restrict__ out,
                                            int K, int N, int bx, int by,
                                            unsigned short* T)
{
    const int n0 = bx * 64, k0 = by * 64;
    const int tid = threadIdx.x;
#pragma unroll
    for (int i = 0; i < 4; ++i) {
        int f = tid + i * 256;
        int r = f >> 4;
        int c4 = (f & 15) * 4;
        float4 v = *reinterpret_cast<const float4*>(&in[(size_t)(k0 + r) * N + n0 + c4]);
        bf16x4 pk = { (short)f2bf(v.x), (short)f2bf(v.y),
                      (short)f2bf(v.z), (short)f2bf(v.w) };
        *reinterpret_cast<bf16x4*>(&T[r * 72 + c4]) = pk;
    }
    __syncthreads();
#pragma unroll
    for (int i = 0; i < 2; ++i) {
        int f = tid + i * 256;
        int nn = f >> 3;
        int s8 = (f & 7) * 8;
        bf16x8 o;
#pragma unroll
        for (int j = 0; j < 8; ++j) o[j] = T[(s8 + j) * 72 + nn];
        *reinterpret_cast<bf16x8*>(&out[(size_t)(n0 + nn) * K + k0 + s8]) = o;
    }
}

// kv v-part [b][s][512+g*128+d] -> vt [b*4+g][d][s], one 64-seq tile
__device__ __forceinline__ void vtrans_body(const unsigned short* __restrict__ kv,
                                            unsigned short* __restrict__ vt,
                                            int bx, int bg, unsigned short* T)
{
    const int b = bg >> 2, g = bg & 3;
    const int s0 = bx * 64;
    const int tid = threadIdx.x;
#pragma unroll
    for (int i = 0; i < 4; ++i) {
        int f = tid + i * 256;
        int sl = f >> 4;
        int d0 = (f & 15) * 8;
        bf16x8 v = *reinterpret_cast<const bf16x8*>(
            &kv[(size_t)(b * 2048 + s0 + sl) * 1024 + 512 + g * 128 + d0]);
        bf16x4 lo = { v[0], v[1], v[2], v[3] };
        bf16x4 hi = { v[4], v[5], v[6], v[7] };
        *reinterpret_cast<bf16x4*>(&T[sl * 140 + d0])     = lo;
        *reinterpret_cast<bf16x4*>(&T[sl * 140 + d0 + 4]) = hi;
    }
    __syncthreads();
#pragma unroll
    for (int i = 0; i < 4; ++i) {
        int f = tid + i * 256;
        int d = f >> 3;
        int s8 = (f & 7) * 8;
        bf16x8 o;
#pragma unroll
        for (int j = 0; j < 8; ++j) o[j] = T[(s8 + j) * 140 + d];
        *reinterpret_cast<bf16x8*>(
            &vt[(size_t)(bg * 128 + d) * 2048 + s0 + s8]) = o;
    }
}

// prep1: xcvt (4096) | wtrans wq (1024) | wtrans wkv (512)  = 5632 blocks
__global__ __launch_bounds__(256)
void prep1_kernel(const float* __restrict__ x, unsigned short* __restrict__ xbf,
                  const float* __restrict__ w_q, unsigned short* __restrict__ wqT,
                  const float* __restrict__ w_kv, unsigned short* __restrict__ wkvT)
{
    __shared__ __align__(16) unsigned short T[64 * 72];
    const int bid = blockIdx.x;
    if (bid < 4096) {
        xcvt_body(x, xbf, bid);
    } else if (bid < 4096 + 1024) {
        int r = bid - 4096;
        wtrans_body(w_q, wqT, 2048, 2048, r & 31, r >> 5, T);
    } else {
        int r = bid - 5120;
        wtrans_body(w_kv, wkvT, 2048, 1024, r & 15, r >> 4, T);
    }
}

// prep2: wtrans wdense (1024) | vtrans (256)  = 1280 blocks
__global__ __launch_bounds__(256)
void prep2_kernel(const float* __restrict__ w_dense, unsigned short* __restrict__ wdT,
                  const unsigned short* __restrict__ kv, unsigned short* __restrict__ vt)
{
    __shared__ __align__(16) unsigned short T[64 * 140];
    const int bid = blockIdx.x;
    if (bid < 1024) {
        wtrans_body(w_dense, wdT, 2048, 2048, bid & 31, bid >> 5, T);
    } else {
        int r = bid - 1024;
        vtrans_body(kv, vt, r & 31, r >> 5, T);
    }
}

// ---------------------------------------------------------------------------
// qkv GEMM: BK=32 triple-buffer, depth-2 prefetch, vmcnt(8), XCD swizzle.
// Epilogue: q cols scaled by scale*log2(e); kv cols to C1.
// ---------------------------------------------------------------------------
__global__ __launch_bounds__(256)
void gemm_qkv_kernel(const unsigned short* __restrict__ A,
                     const unsigned short* __restrict__ BT,
                     void* __restrict__ C0v, void* __restrict__ C1v,
                     int M, int N, int K)
{
    __shared__ __align__(16) unsigned short Alds[3][128 * 32];   // 3 x 8KB
    __shared__ __align__(16) unsigned short Blds[3][128 * 32];   // 3 x 8KB

    const int tid = threadIdx.x;
    const int lane = tid & 63;
    const int wid = tid >> 6;
    const int wr = wid >> 1, wc = wid & 1;
    const int nbx = gridDim.x;
    const int lin = blockIdx.y * nbx + blockIdx.x;
    const int sl = xcd_swizzle(lin, nbx * gridDim.y);
    const int m0 = (sl / nbx) * 128;
    const int n0 = (sl % nbx) * 128;
    const int l16 = lane & 15, lg = lane >> 4;

    f32x4 acc[4][4];
#pragma unroll
    for (int m = 0; m < 4; ++m)
#pragma unroll
        for (int n = 0; n < 4; ++n) acc[m][n] = (f32x4){0.f, 0.f, 0.f, 0.f};

    int srow[2], skb[2];
#pragma unroll
    for (int i = 0; i < 2; ++i) {
        int L = i * 4096 + tid * 16;
        int R = L >> 7, c = L & 127;
        int cp = c ^ ((R & 7) << 4);
        srow[i] = 2 * R + (cp >> 6);
        skb[i]  = cp & 63;
    }

    auto stage = [&](int kt, int bi) {
#pragma unroll
        for (int i = 0; i < 2; ++i) {
            int L = i * 4096 + tid * 16;
            gl_lds16((const char*)A + ((size_t)(m0 + srow[i]) * K + kt) * 2 + skb[i],
                     (char*)(&Alds[bi][0]) + L);
            gl_lds16((const char*)BT + ((size_t)(n0 + srow[i]) * K + kt) * 2 + skb[i],
                     (char*)(&Blds[bi][0]) + L);
        }
    };

    const int NK = K / 32;
    stage(0, 0);
    stage(32, 1);

    for (int t = 0; t < NK; ++t) {
        const int bi = t % 3;
        if (t + 2 < NK) {
            stage((t + 2) * 32, (t + 2) % 3);           // depth-2 prefetch
            asm volatile("s_waitcnt vmcnt(8)" ::: "memory");   // tile t landed
        } else if (t + 1 < NK) {
            asm volatile("s_waitcnt vmcnt(4)" ::: "memory");
        } else {
            asm volatile("s_waitcnt vmcnt(0)" ::: "memory");
        }
        __builtin_amdgcn_s_barrier();

        const char* Ab = (const char*)(&Alds[bi][0]);
        const char* Bb = (const char*)(&Blds[bi][0]);

        bf16x8 af[4], bf[4];
#pragma unroll
        for (int m = 0; m < 4; ++m) {
            int row = wr * 64 + m * 16 + l16;
            int byte = (row >> 1) * 128 +
                       ((((row & 1) << 6) + lg * 16) ^ (((row >> 1) & 7) << 4));
            af[m] = *reinterpret_cast<const bf16x8*>(Ab + byte);
        }
#pragma unroll
        for (int n = 0; n < 4; ++n) {
            int row = wc * 64 + n * 16 + l16;
            int byte = (row >> 1) * 128 +
                       ((((row & 1) << 6) + lg * 16) ^ (((row >> 1) & 7) << 4));
            bf[n] = *reinterpret_cast<const bf16x8*>(Bb + byte);
        }
#pragma unroll
        for (int m = 0; m < 4; ++m)
#pragma unroll
            for (int n = 0; n < 4; ++n)
                acc[m][n] = __builtin_amdgcn_mfma_f32_16x16x32_bf16(
                    af[m], bf[n], acc[m][n], 0, 0, 0);

        __builtin_amdgcn_s_barrier();   // all reads of buf[bi] done before
    }                                   // it is restaged at t+3

#pragma unroll
    for (int m = 0; m < 4; ++m) {
#pragma unroll
        for (int n = 0; n < 4; ++n) {
#pragma unroll
            for (int r = 0; r < 4; ++r) {
                int row = m0 + wr * 64 + m * 16 + lg * 4 + r;
                int col = n0 + wc * 64 + n * 16 + l16;
                float val = acc[m][n][r];
                if (n0 < 2048)   // q: fold scale * log2(e) for exp2 softmax
                    ((unsigned short*)C0v)[(size_t)row * 2048 + col] =
                        f2bf(val * 0.12751879523209208f);
                else
                    ((unsigned short*)C1v)[(size_t)row * 1024 + (col - 2048)] = f2bf(val);
            }
        }
    }
}

// ---------------------------------------------------------------------------
// Dense GEMM: BK=64 dbuf + XCD swizzle.  fp32 out.
// ---------------------------------------------------------------------------
__global__ __launch_bounds__(256)
void gemm_dense_kernel(const unsigned short* __restrict__ A,
                       const unsigned short* __restrict__ BT,
                       float* __restrict__ C, int M, int N, int K)
{
    __shared__ __align__(16) unsigned short Alds[2][128 * 64];
    __shared__ __align__(16) unsigned short Blds[2][128 * 64];

    const int tid = threadIdx.x;
    const int lane = tid & 63;
    const int wid = tid >> 6;
    const int wr = wid >> 1, wc = wid & 1;
    const int nbx = gridDim.x;
    const int lin = blockIdx.y * nbx + blockIdx.x;
    const int sl = xcd_swizzle(lin, nbx * gridDim.y);
    const int m0 = (sl / nbx) * 128;
    const int n0 = (sl % nbx) * 128;
    const int l16 = lane & 15, lg = lane >> 4;

    f32x4 acc[4][4];
#pragma unroll
    for (int m = 0; m < 4; ++m)
#pragma unroll
        for (int n = 0; n < 4; ++n) acc[m][n] = (f32x4){0.f, 0.f, 0.f, 0.f};

    auto stage = [&](int kt, int bi) {
#pragma unroll
        for (int i = 0; i < 4; ++i) {
            int row = i * 32 + (tid >> 3);
            int cb = ((tid & 7) * 16) ^ ((row & 7) << 4);
            gl_lds16((const char*)A + ((size_t)(m0 + row) * K + kt) * 2 + cb,
                     (char*)(&Alds[bi][0]) + i * 4096 + wid * 1024);
            gl_lds16((const char*)BT + ((size_t)(n0 + row) * K + kt) * 2 + cb,
                     (char*)(&Blds[bi][0]) + i * 4096 + wid * 1024);
        }
    };

    const int NK = K / 64;
    stage(0, 0);
    int cur = 0;

    for (int kti = 0; kti < NK; ++kti) {
        if (kti + 1 < NK) {
            stage((kti + 1) * 64, cur ^ 1);
            asm volatile("s_waitcnt vmcnt(8)" ::: "memory");
        } else {
            asm volatile("s_waitcnt vmcnt(0)" ::: "memory");
        }
        __builtin_amdgcn_s_barrier();

        const char* Ab = (const char*)(&Alds[cur][0]);
        const char* Bb = (const char*)(&Blds[cur][0]);

        bf16x8 af[2][4], bf[2][4];
#pragma unroll
        for (int kd = 0; kd < 2; ++kd) {
#pragma unroll
            for (int m = 0; m < 4; ++m) {
                int row = wr * 64 + m * 16 + l16;
                af[kd][m] = *reinterpret_cast<const bf16x8*>(
                    Ab + row * 128 + ((kd * 64 + lg * 16) ^ ((row & 7) << 4)));
            }
#pragma unroll
            for (int n = 0; n < 4; ++n) {
                int row = wc * 64 + n * 16 + l16;
                bf[kd][n] = *reinterpret_cast<const bf16x8*>(
                    Bb + row * 128 + ((kd * 64 + lg * 16) ^ ((row & 7) << 4)));
            }
        }
#pragma unroll
        for (int kd = 0; kd < 2; ++kd)
#pragma unroll
            for (int m = 0; m < 4; ++m)
#pragma unroll
                for (int n = 0; n < 4; ++n)
                    acc[m][n] = __builtin_amdgcn_mfma_f32_16x16x32_bf16(
                        af[kd][m], bf[kd][n], acc[m][n], 0, 0, 0);

        __builtin_amdgcn_s_barrier();
        cur ^= 1;
    }

#pragma unroll
    for (int m = 0; m < 4; ++m) {
#pragma unroll
        for (int n = 0; n < 4; ++n) {
#pragma unroll
            for (int r = 0; r < 4; ++r) {
                int row = m0 + wr * 64 + m * 16 + lg * 4 + r;
                int col = n0 + wc * 64 + n * 16 + l16;
                C[(size_t)row * N + col] = acc[m][n][r];
            }
        }
    }
}

// ---------------------------------------------------------------------------
// Flash attention v10 (best measured 72.4us): 16-row q-tiles; block (gb, pi)
// serially processes q-tile 127-pi then pi -> uniform 33 phases/block,
// 512 blocks = 2/CU.  K/V double-buffered, counted vmcnt(8); 72KB LDS.
// Swapped S^T, exp2-direct softmax (scale pre-folded), swizzled P.
// ---------------------------------------------------------------------------
__global__ __launch_bounds__(256)
void attn_kernel(const unsigned short* __restrict__ Q,   // [b][s][h*128+d] (q pre-scaled)
                 const unsigned short* __restrict__ KV,  // [b][s][1024] (k at g*128)
                 const unsigned short* __restrict__ VT,  // [b*4+g][d][s]
                 unsigned short* __restrict__ CTX)       // [b][s][h*128+d]
{
    constexpr int SQ = 2048;
    __shared__ __align__(16) unsigned short Klds[2][64 * 128];   // 32KB
    __shared__ __align__(16) unsigned short Vlds[2][128 * 64];   // 32KB
    __shared__ __align__(16) unsigned short Pl[4][16][64];       //  8KB

    const int tid = threadIdx.x;
    const int lane = tid & 63;
    const int w = tid >> 6;                     // 0..3 = head within group
    const int l16 = lane & 15, lg = lane >> 4;

    const int bid = blockIdx.x;
    const int gb = bid & 7;                     // XCD pin
    const int g = gb & 3, b = gb >> 2;
    const int pi = bid >> 3;                    // 0..63 pair index
    const int hh = g * 4 + w;

    const size_t qbase = (size_t)b * SQ * 2048;
    const char* KVb = (const char*)KV + (size_t)b * SQ * 2048;  // bytes
    const char* VTb = (const char*)VT;

    const int pswz = (l16 & 7) << 3;            // P key-swizzle for this lane

    auto stage = [&](int t, int bi) {
        const int k0 = t * 64;
#pragma unroll
        for (int i = 0; i < 4; ++i) {
            int row = w * 16 + i * 4 + (lane >> 4);
            int scol = ((lane & 15) * 16) ^ ((row & 7) << 4);
            gl_lds16(KVb + (size_t)(k0 + row) * 2048 + g * 256 + scol,
                     (char*)(&Klds[bi][0]) + w * 4096 + i * 1024);
        }
#pragma unroll
        for (int i = 0; i < 4; ++i) {
            int row = w * 32 + i * 8 + (lane >> 3);
            int scol = ((lane & 7) * 16) ^ ((row & 7) << 4);
            gl_lds16(VTb + ((size_t)(gb * 128 + row) * 2048 + k0) * 2 + scol,
                     (char*)(&Vlds[bi][0]) + w * 4096 + i * 1024);
        }
    };

#pragma unroll 1
    for (int seg = 0; seg < 2; ++seg) {
        const int qt = seg ? pi : (127 - pi);   // long tile first
        const int ntiles = qt / 4 + 1;

        bf16x8 qfrag[4];
#pragma unroll
        for (int kd = 0; kd < 4; ++kd)
            qfrag[kd] = *reinterpret_cast<const bf16x8*>(
                &Q[qbase + (size_t)(qt * 16 + l16) * 2048 + hh * 128 + kd * 32 + lg * 8]);

        float lsum = 0.f;
        f32x4 acc[8];
#pragma unroll
        for (int nd = 0; nd < 8; ++nd) acc[nd] = (f32x4){0.f,0.f,0.f,0.f};

        stage(0, 0);

        for (int t = 0; t < ntiles; ++t) {
            const int bi = t & 1;
            const int k0 = t * 64;
            if (t + 1 < ntiles) {
                stage(t + 1, bi ^ 1);                       // prefetch next tile
                asm volatile("s_waitcnt vmcnt(8)" ::: "memory");  // tile t landed
            } else {
                asm volatile("s_waitcnt vmcnt(0)" ::: "memory");
            }
            __builtin_amdgcn_s_barrier();

            const char* Kb = (const char*)(&Klds[bi][0]);
            const char* Vb = (const char*)(&Vlds[bi][0]);

            // ---- S^T = K Q^T (swapped operands); q pre-scaled ----
            f32x4 st[4];
#pragma unroll
            for (int nf = 0; nf < 4; ++nf) st[nf] = (f32x4){0.f,0.f,0.f,0.f};
            __builtin_amdgcn_s_setprio(1);
#pragma unroll
            for (int nf = 0; nf < 4; ++nf) {
                int row = nf * 16 + l16;                    // key row
#pragma unroll
                for (int kd = 0; kd < 4; ++kd) {
                    bf16x8 kf = *reinterpret_cast<const bf16x8*>(
                        Kb + row * 256 + ((kd * 64 + lg * 16) ^ ((row & 7) << 4)));
                    st[nf] = __builtin_amdgcn_mfma_f32_16x16x32_bf16(
                        kf, qfrag[kd], st[nf], 0, 0, 0);
                }
            }
            __builtin_amdgcn_s_setprio(0);

            // ---- softmax (exp2 direct, no max), pack P -> LDS ----
            const bool diag = (t == ntiles - 1);
            {
                float lacc = 0.f;
                const int q = qt * 16 + l16;
#pragma unroll
                for (int nf = 0; nf < 4; ++nf) {
                    float cs0 = st[nf][0];
                    float cs1 = st[nf][1];
                    float cs2 = st[nf][2];
                    float cs3 = st[nf][3];
                    if (diag) {
                        const int keyb = k0 + nf * 16 + lg * 4;
                        if (keyb + 0 > q) cs0 = -INFINITY;
                        if (keyb + 1 > q) cs1 = -INFINITY;
                        if (keyb + 2 > q) cs2 = -INFINITY;
                        if (keyb + 3 > q) cs3 = -INFINITY;
                    }
                    float p0 = exp2f(cs0), p1 = exp2f(cs1);
                    float p2 = exp2f(cs2), p3 = exp2f(cs3);
                    lacc += (p0 + p1) + (p2 + p3);
                    uint2 pk = { cvtpk_bf16(p0, p1), cvtpk_bf16(p2, p3) };
                    *reinterpret_cast<uint2*>(
                        &Pl[w][l16][(nf * 16 + lg * 4) ^ pswz]) = pk;
                }
                lacc += __shfl_xor(lacc, 16, 64);
                lacc += __shfl_xor(lacc, 32, 64);
                lsum += lacc;
            }

            // ---- ctx^T += V^T P^T ----
            __builtin_amdgcn_s_setprio(1);
#pragma unroll
            for (int kc = 0; kc < 2; ++kc) {
                bf16x8 pf = *reinterpret_cast<const bf16x8*>(
                    &Pl[w][l16][(kc * 32 + lg * 8) ^ pswz]);
#pragma unroll
                for (int nd = 0; nd < 8; ++nd) {
                    int row = nd * 16 + l16;                // d row of V^T
                    bf16x8 vf = *reinterpret_cast<const bf16x8*>(
                        Vb + row * 128 + ((kc * 64 + lg * 16) ^ ((row & 7) << 4)));
                    acc[nd] = __builtin_amdgcn_mfma_f32_16x16x32_bf16(
                        vf, pf, acc[nd], 0, 0, 0);
                }
            }
            __builtin_amdgcn_s_setprio(0);
            __builtin_amdgcn_s_barrier();   // buf[bi] reads done before restage
        }

        // ---- epilogue: acc = ctx^T (col=q, row=d) ----
        {
            float inv = 1.0f / lsum;
            const int q = qt * 16 + l16;
#pragma unroll
            for (int nd = 0; nd < 8; ++nd) {
                bf16x4 o = { (short)f2bf(acc[nd][0] * inv),
                             (short)f2bf(acc[nd][1] * inv),
                             (short)f2bf(acc[nd][2] * inv),
                             (short)f2bf(acc[nd][3] * inv) };
                *reinterpret_cast<bf16x4*>(
                    &CTX[qbase + (size_t)q * 2048 + hh * 128 + nd * 16 + lg * 4]) = o;
            }
        }
    }
}

// ---------------------------------------------------------------------------
extern "C" void kernel_launch(void* const* d_in, const int* in_sizes, int n_in,
                              void* d_out, int out_size, void* d_ws, size_t ws_size,
                              hipStream_t stream)
{
    const float* x       = (const float*)d_in[0];
    const float* w_q     = (const float*)d_in[1];
    const float* w_kv    = (const float*)d_in[2];
    const float* w_dense = (const float*)d_in[3];

    const int M = 4096;                            // B*SQ

    // ws (36 MB): kv 8 @0 | ctx 16 @8 | wqT 8 @24 (reused as wdT) | wkvT 4 @32
    char* ws = (char*)d_ws;
    unsigned short* kv_buf  = (unsigned short*)(ws);
    unsigned short* ctx_buf = (unsigned short*)(ws + (8u << 20));
    unsigned short* wqT     = (unsigned short*)(ws + (24u << 20));
    unsigned short* wkvT    = (unsigned short*)(ws + (32u << 20));
    unsigned short* wdT     = wqT;
    // d_out (32 MB): xbf [0:16M] (dead after qkv GEMM) | q_buf [16:32M];
    // vt [0:4M] reuses xbf's region; dense GEMM finally overwrites all of d_out.
    unsigned short* xbf    = (unsigned short*)d_out;
    unsigned short* q_buf  = (unsigned short*)d_out + (size_t)M * 2048;
    unsigned short* vt_buf = (unsigned short*)d_out;

    dim3 blk(256);
    prep1_kernel<<<dim3(5632), blk, 0, stream>>>(x, xbf, w_q, wqT, w_kv, wkvT);
    gemm_qkv_kernel<<<dim3(24, 32), blk, 0, stream>>>(
        xbf, wqT, (void*)q_buf, (void*)kv_buf, M, 3072, 2048);
    prep2_kernel<<<dim3(1280), blk, 0, stream>>>(w_dense, wdT, kv_buf, vt_buf);
    attn_kernel<<<dim3(512), blk, 0, stream>>>(q_buf, kv_buf, vt_buf, ctx_buf);
    gemm_dense_kernel<<<dim3(16, 32), blk, 0, stream>>>(
        ctx_buf, wdT, (float*)d_out, M, 2048, 2048);
}

// Round 23
// 172.340 us; speedup vs baseline: 1.1065x; 1.0629x over previous
//
#include <hip/hip_runtime.h>
#include <hip/hip_bf16.h>

// ---------------------------------------------------------------------------
// Fused GQA attention block: out = dense( attn( x*Wq, x*Wkv ) )
// B=2, SQ=2048, HIDDEN=2048, HEADS=16, GROUPS=4, KVC=128, causal, scale=1/sqrt(128)
// R23: qkv GEMM -> 128x192 tile, BK=64 double-buffer (80KB LDS, 512 blocks
//      = 2/CU exact fill, dense-GEMM barrier amortization).  Epilogue q/kv
//      split per-column (tiles straddle col 2048).  Rest frozen from R22.
// ---------------------------------------------------------------------------

typedef __attribute__((ext_vector_type(4))) float f32x4;
typedef __attribute__((ext_vector_type(8))) short bf16x8;
typedef __attribute__((ext_vector_type(4))) short bf16x4;

__device__ __forceinline__ unsigned short f2bf(float f) {
    unsigned u = __builtin_bit_cast(unsigned, f);
    unsigned r = u + 0x7fffu + ((u >> 16) & 1u);   // round-to-nearest-even
    return (unsigned short)(r >> 16);
}

__device__ __forceinline__ unsigned cvtpk_bf16(float lo, float hi) {
    unsigned r;
    asm("v_cvt_pk_bf16_f32 %0, %1, %2" : "=v"(r) : "v"(lo), "v"(hi));
    return r;
}

// async global->LDS, 16B/lane; LDS dest = wave-uniform base + lane*16
__device__ __forceinline__ void gl_lds16(const void* g, void* l) {
    __builtin_amdgcn_global_load_lds(
        (const __attribute__((address_space(1))) unsigned int*)g,
        (__attribute__((address_space(3))) unsigned int*)l, 16, 0, 0);
}

// XCD-aware bijective remap (requires nwg % 8 == 0)
__device__ __forceinline__ int xcd_swizzle(int lin, int nwg) {
    return (lin & 7) * (nwg >> 3) + (lin >> 3);
}

// ---------------------------------------------------------------------------
// Fused prep bodies
// ---------------------------------------------------------------------------
__device__ __forceinline__ void xcvt_body(const float* __restrict__ in,
                                          unsigned short* __restrict__ out,
                                          int blk)
{
    size_t i = ((size_t)blk * 256 + threadIdx.x) * 8;
    float4 a = *reinterpret_cast<const float4*>(&in[i]);
    float4 b = *reinterpret_cast<const float4*>(&in[i + 4]);
    bf16x8 o = { (short)f2bf(a.x), (short)f2bf(a.y),
                 (short)f2bf(a.z), (short)f2bf(a.w),
                 (short)f2bf(b.x), (short)f2bf(b.y),
                 (short)f2bf(b.z), (short)f2bf(b.w) };
    *reinterpret_cast<bf16x8*>(&out[i]) = o;
}

// fp32 [K][N] -> bf16 [N][K], one 64x64 tile; T is 64x72 shared scratch
__device__ __forceinline__ void wtrans_body(const float* __restrict__ in,
                                            unsigned short* __restrict__ out,
                                            int K, int N, int bx, int by,
                                            unsigned short* T)
{
    const int n0 = bx * 64, k0 = by * 64;
    const int tid = threadIdx.x;
#pragma unroll
    for (int i = 0; i < 4; ++i) {
        int f = tid + i * 256;
        int r = f >> 4;
        int c4 = (f & 15) * 4;
        float4 v = *reinterpret_cast<const float4*>(&in[(size_t)(k0 + r) * N + n0 + c4]);
        bf16x4 pk = { (short)f2bf(v.x), (short)f2bf(v.y),
                      (short)f2bf(v.z), (short)f2bf(v.w) };
        *reinterpret_cast<bf16x4*>(&T[r * 72 + c4]) = pk;
    }
    __syncthreads();
#pragma unroll
    for (int i = 0; i < 2; ++i) {
        int f = tid + i * 256;
        int nn = f >> 3;
        int s8 = (f & 7) * 8;
        bf16x8 o;
#pragma unroll
        for (int j = 0; j < 8; ++j) o[j] = T[(s8 + j) * 72 + nn];
        *reinterpret_cast<bf16x8*>(&out[(size_t)(n0 + nn) * K + k0 + s8]) = o;
    }
}

// kv v-part [b][s][512+g*128+d] -> vt [b*4+g][d][s], one 64-seq tile
__device__ __forceinline__ void vtrans_body(const unsigned short* __restrict__ kv,
                                            unsigned short* __restrict__ vt,
                                            int bx, int bg, unsigned short* T)
{
    const int b = bg >> 2, g = bg & 3;
    const int s0 = bx * 64;
    const int tid = threadIdx.x;
#pragma unroll
    for (int i = 0; i < 4; ++i) {
        int f = tid + i * 256;
        int sl = f >> 4;
        int d0 = (f & 15) * 8;
        bf16x8 v = *reinterpret_cast<const bf16x8*>(
            &kv[(size_t)(b * 2048 + s0 + sl) * 1024 + 512 + g * 128 + d0]);
        bf16x4 lo = { v[0], v[1], v[2], v[3] };
        bf16x4 hi = { v[4], v[5], v[6], v[7] };
        *reinterpret_cast<bf16x4*>(&T[sl * 140 + d0])     = lo;
        *reinterpret_cast<bf16x4*>(&T[sl * 140 + d0 + 4]) = hi;
    }
    __syncthreads();
#pragma unroll
    for (int i = 0; i < 4; ++i) {
        int f = tid + i * 256;
        int d = f >> 3;
        int s8 = (f & 7) * 8;
        bf16x8 o;
#pragma unroll
        for (int j = 0; j < 8; ++j) o[j] = T[(s8 + j) * 140 + d];
        *reinterpret_cast<bf16x8*>(
            &vt[(size_t)(bg * 128 + d) * 2048 + s0 + s8]) = o;
    }
}

// prep1: xcvt (4096) | wtrans wq (1024) | wtrans wkv (512)  = 5632 blocks
__global__ __launch_bounds__(256)
void prep1_kernel(const float* __restrict__ x, unsigned short* __restrict__ xbf,
                  const float* __restrict__ w_q, unsigned short* __restrict__ wqT,
                  const float* __restrict__ w_kv, unsigned short* __restrict__ wkvT)
{
    __shared__ __align__(16) unsigned short T[64 * 72];
    const int bid = blockIdx.x;
    if (bid < 4096) {
        xcvt_body(x, xbf, bid);
    } else if (bid < 4096 + 1024) {
        int r = bid - 4096;
        wtrans_body(w_q, wqT, 2048, 2048, r & 31, r >> 5, T);
    } else {
        int r = bid - 5120;
        wtrans_body(w_kv, wkvT, 2048, 1024, r & 15, r >> 4, T);
    }
}

// prep2: wtrans wdense (1024) | vtrans (256)  = 1280 blocks
__global__ __launch_bounds__(256)
void prep2_kernel(const float* __restrict__ w_dense, unsigned short* __restrict__ wdT,
                  const unsigned short* __restrict__ kv, unsigned short* __restrict__ vt)
{
    __shared__ __align__(16) unsigned short T[64 * 140];
    const int bid = blockIdx.x;
    if (bid < 1024) {
        wtrans_body(w_dense, wdT, 2048, 2048, bid & 31, bid >> 5, T);
    } else {
        int r = bid - 1024;
        vtrans_body(kv, vt, r & 31, r >> 5, T);
    }
}

// ---------------------------------------------------------------------------
// qkv GEMM (R23): 128x192 tile, BK=64 double-buffer, vmcnt(10), XCD swizzle.
// Grid 16x32 = 512 blocks = 2/CU exact fill; LDS = (16K A + 24K B) x 2 = 80KB.
// 4 waves (2x2): wave = 64 rows x 96 cols (4x6 16x16x32 frags).
// Epilogue per-column q/kv split (192-wide tiles straddle col 2048);
// q cols scaled by scale*log2(e).
// ---------------------------------------------------------------------------
__global__ __launch_bounds__(256)
void gemm_qkv_kernel(const unsigned short* __restrict__ A,
                     const unsigned short* __restrict__ BT,
                     void* __restrict__ C0v, void* __restrict__ C1v,
                     int M, int N, int K)
{
    __shared__ __align__(16) unsigned short Alds[2][128 * 64];   // 2 x 16KB
    __shared__ __align__(16) unsigned short Blds[2][192 * 64];   // 2 x 24KB

    const int tid = threadIdx.x;
    const int lane = tid & 63;
    const int wid = tid >> 6;
    const int wr = wid >> 1, wc = wid & 1;
    const int nbx = gridDim.x;                  // 16 n-tiles of 192
    const int lin = blockIdx.y * nbx + blockIdx.x;
    const int sl = xcd_swizzle(lin, nbx * gridDim.y);
    const int m0 = (sl / nbx) * 128;
    const int n0 = (sl % nbx) * 192;
    const int l16 = lane & 15, lg = lane >> 4;

    f32x4 acc[4][6];
#pragma unroll
    for (int m = 0; m < 4; ++m)
#pragma unroll
        for (int n = 0; n < 6; ++n) acc[m][n] = (f32x4){0.f, 0.f, 0.f, 0.f};

    // stage one BK=64 tile: A 128x64 (4 issues) + B 192x64 (6 issues)
    auto stage = [&](int kt, int bi) {
#pragma unroll
        for (int i = 0; i < 4; ++i) {
            int row = i * 32 + (tid >> 3);
            int cb = ((tid & 7) * 16) ^ ((row & 7) << 4);
            gl_lds16((const char*)A + ((size_t)(m0 + row) * K + kt) * 2 + cb,
                     (char*)(&Alds[bi][0]) + i * 4096 + wid * 1024);
        }
#pragma unroll
        for (int i = 0; i < 6; ++i) {
            int row = i * 32 + (tid >> 3);
            int cb = ((tid & 7) * 16) ^ ((row & 7) << 4);
            gl_lds16((const char*)BT + ((size_t)(n0 + row) * K + kt) * 2 + cb,
                     (char*)(&Blds[bi][0]) + i * 4096 + wid * 1024);
        }
    };

    const int NK = K / 64;
    stage(0, 0);
    int cur = 0;

    for (int kti = 0; kti < NK; ++kti) {
        if (kti + 1 < NK) {
            stage((kti + 1) * 64, cur ^ 1);
            asm volatile("s_waitcnt vmcnt(10)" ::: "memory");  // tile kti landed
        } else {
            asm volatile("s_waitcnt vmcnt(0)" ::: "memory");
        }
        __builtin_amdgcn_s_barrier();

        const char* Ab = (const char*)(&Alds[cur][0]);
        const char* Bb = (const char*)(&Blds[cur][0]);

        bf16x8 af[2][4], bf[2][6];
#pragma unroll
        for (int kd = 0; kd < 2; ++kd) {
#pragma unroll
            for (int m = 0; m < 4; ++m) {
                int row = wr * 64 + m * 16 + l16;
                af[kd][m] = *reinterpret_cast<const bf16x8*>(
                    Ab + row * 128 + ((kd * 64 + lg * 16) ^ ((row & 7) << 4)));
            }
#pragma unroll
            for (int n = 0; n < 6; ++n) {
                int row = wc * 96 + n * 16 + l16;
                bf[kd][n] = *reinterpret_cast<const bf16x8*>(
                    Bb + row * 128 + ((kd * 64 + lg * 16) ^ ((row & 7) << 4)));
            }
        }
#pragma unroll
        for (int kd = 0; kd < 2; ++kd)
#pragma unroll
            for (int m = 0; m < 4; ++m)
#pragma unroll
                for (int n = 0; n < 6; ++n)
                    acc[m][n] = __builtin_amdgcn_mfma_f32_16x16x32_bf16(
                        af[kd][m], bf[kd][n], acc[m][n], 0, 0, 0);

        __builtin_amdgcn_s_barrier();
        cur ^= 1;
    }

    // ---- epilogue: per-column q/kv routing ----
#pragma unroll
    for (int m = 0; m < 4; ++m) {
#pragma unroll
        for (int n = 0; n < 6; ++n) {
#pragma unroll
            for (int r = 0; r < 4; ++r) {
                int row = m0 + wr * 64 + m * 16 + lg * 4 + r;
                int col = n0 + wc * 96 + n * 16 + l16;
                float val = acc[m][n][r];
                if (col < 2048)   // q: fold scale * log2(e) for exp2 softmax
                    ((unsigned short*)C0v)[(size_t)row * 2048 + col] =
                        f2bf(val * 0.12751879523209208f);
                else
                    ((unsigned short*)C1v)[(size_t)row * 1024 + (col - 2048)] = f2bf(val);
            }
        }
    }
}

// ---------------------------------------------------------------------------
// Dense GEMM: BK=64 dbuf + XCD swizzle.  fp32 out.  (frozen R22)
// ---------------------------------------------------------------------------
__global__ __launch_bounds__(256)
void gemm_dense_kernel(const unsigned short* __restrict__ A,
                       const unsigned short* __restrict__ BT,
                       float* __restrict__ C, int M, int N, int K)
{
    __shared__ __align__(16) unsigned short Alds[2][128 * 64];
    __shared__ __align__(16) unsigned short Blds[2][128 * 64];

    const int tid = threadIdx.x;
    const int lane = tid & 63;
    const int wid = tid >> 6;
    const int wr = wid >> 1, wc = wid & 1;
    const int nbx = gridDim.x;
    const int lin = blockIdx.y * nbx + blockIdx.x;
    const int sl = xcd_swizzle(lin, nbx * gridDim.y);
    const int m0 = (sl / nbx) * 128;
    const int n0 = (sl % nbx) * 128;
    const int l16 = lane & 15, lg = lane >> 4;

    f32x4 acc[4][4];
#pragma unroll
    for (int m = 0; m < 4; ++m)
#pragma unroll
        for (int n = 0; n < 4; ++n) acc[m][n] = (f32x4){0.f, 0.f, 0.f, 0.f};

    auto stage = [&](int kt, int bi) {
#pragma unroll
        for (int i = 0; i < 4; ++i) {
            int row = i * 32 + (tid >> 3);
            int cb = ((tid & 7) * 16) ^ ((row & 7) << 4);
            gl_lds16((const char*)A + ((size_t)(m0 + row) * K + kt) * 2 + cb,
                     (char*)(&Alds[bi][0]) + i * 4096 + wid * 1024);
            gl_lds16((const char*)BT + ((size_t)(n0 + row) * K + kt) * 2 + cb,
                     (char*)(&Blds[bi][0]) + i * 4096 + wid * 1024);
        }
    };

    const int NK = K / 64;
    stage(0, 0);
    int cur = 0;

    for (int kti = 0; kti < NK; ++kti) {
        if (kti + 1 < NK) {
            stage((kti + 1) * 64, cur ^ 1);
            asm volatile("s_waitcnt vmcnt(8)" ::: "memory");
        } else {
            asm volatile("s_waitcnt vmcnt(0)" ::: "memory");
        }
        __builtin_amdgcn_s_barrier();

        const char* Ab = (const char*)(&Alds[cur][0]);
        const char* Bb = (const char*)(&Blds[cur][0]);

        bf16x8 af[2][4], bf[2][4];
#pragma unroll
        for (int kd = 0; kd < 2; ++kd) {
#pragma unroll
            for (int m = 0; m < 4; ++m) {
                int row = wr * 64 + m * 16 + l16;
                af[kd][m] = *reinterpret_cast<const bf16x8*>(
                    Ab + row * 128 + ((kd * 64 + lg * 16) ^ ((row & 7) << 4)));
            }
#pragma unroll
            for (int n = 0; n < 4; ++n) {
                int row = wc * 64 + n * 16 + l16;
                bf[kd][n] = *reinterpret_cast<const bf16x8*>(
                    Bb + row * 128 + ((kd * 64 + lg * 16) ^ ((row & 7) << 4)));
            }
        }
#pragma unroll
        for (int kd = 0; kd < 2; ++kd)
#pragma unroll
            for (int m = 0; m < 4; ++m)
#pragma unroll
                for (int n = 0; n < 4; ++n)
                    acc[m][n] = __builtin_amdgcn_mfma_f32_16x16x32_bf16(
                        af[kd][m], bf[kd][n], acc[m][n], 0, 0, 0);

        __builtin_amdgcn_s_barrier();
        cur ^= 1;
    }

#pragma unroll
    for (int m = 0; m < 4; ++m) {
#pragma unroll
        for (int n = 0; n < 4; ++n) {
#pragma unroll
            for (int r = 0; r < 4; ++r) {
                int row = m0 + wr * 64 + m * 16 + lg * 4 + r;
                int col = n0 + wc * 64 + n * 16 + l16;
                C[(size_t)row * N + col] = acc[m][n][r];
            }
        }
    }
}

// ---------------------------------------------------------------------------
// Flash attention v10 (best measured 72.4us): 16-row q-tiles; block (gb, pi)
// serially processes q-tile 127-pi then pi -> uniform 33 phases/block,
// 512 blocks = 2/CU.  K/V double-buffered, counted vmcnt(8); 72KB LDS.
// Swapped S^T, exp2-direct softmax (scale pre-folded), swizzled P.
// ---------------------------------------------------------------------------
__global__ __launch_bounds__(256)
void attn_kernel(const unsigned short* __restrict__ Q,   // [b][s][h*128+d] (q pre-scaled)
                 const unsigned short* __restrict__ KV,  // [b][s][1024] (k at g*128)
                 const unsigned short* __restrict__ VT,  // [b*4+g][d][s]
                 unsigned short* __restrict__ CTX)       // [b][s][h*128+d]
{
    constexpr int SQ = 2048;
    __shared__ __align__(16) unsigned short Klds[2][64 * 128];   // 32KB
    __shared__ __align__(16) unsigned short Vlds[2][128 * 64];   // 32KB
    __shared__ __align__(16) unsigned short Pl[4][16][64];       //  8KB

    const int tid = threadIdx.x;
    const int lane = tid & 63;
    const int w = tid >> 6;                     // 0..3 = head within group
    const int l16 = lane & 15, lg = lane >> 4;

    const int bid = blockIdx.x;
    const int gb = bid & 7;                     // XCD pin
    const int g = gb & 3, b = gb >> 2;
    const int pi = bid >> 3;                    // 0..63 pair index
    const int hh = g * 4 + w;

    const size_t qbase = (size_t)b * SQ * 2048;
    const char* KVb = (const char*)KV + (size_t)b * SQ * 2048;  // bytes
    const char* VTb = (const char*)VT;

    const int pswz = (l16 & 7) << 3;            // P key-swizzle for this lane

    auto stage = [&](int t, int bi) {
        const int k0 = t * 64;
#pragma unroll
        for (int i = 0; i < 4; ++i) {
            int row = w * 16 + i * 4 + (lane >> 4);
            int scol = ((lane & 15) * 16) ^ ((row & 7) << 4);
            gl_lds16(KVb + (size_t)(k0 + row) * 2048 + g * 256 + scol,
                     (char*)(&Klds[bi][0]) + w * 4096 + i * 1024);
        }
#pragma unroll
        for (int i = 0; i < 4; ++i) {
            int row = w * 32 + i * 8 + (lane >> 3);
            int scol = ((lane & 7) * 16) ^ ((row & 7) << 4);
            gl_lds16(VTb + ((size_t)(gb * 128 + row) * 2048 + k0) * 2 + scol,
                     (char*)(&Vlds[bi][0]) + w * 4096 + i * 1024);
        }
    };

#pragma unroll 1
    for (int seg = 0; seg < 2; ++seg) {
        const int qt = seg ? pi : (127 - pi);   // long tile first
        const int ntiles = qt / 4 + 1;

        bf16x8 qfrag[4];
#pragma unroll
        for (int kd = 0; kd < 4; ++kd)
            qfrag[kd] = *reinterpret_cast<const bf16x8*>(
                &Q[qbase + (size_t)(qt * 16 + l16) * 2048 + hh * 128 + kd * 32 + lg * 8]);

        float lsum = 0.f;
        f32x4 acc[8];
#pragma unroll
        for (int nd = 0; nd < 8; ++nd) acc[nd] = (f32x4){0.f,0.f,0.f,0.f};

        stage(0, 0);

        for (int t = 0; t < ntiles; ++t) {
            const int bi = t & 1;
            const int k0 = t * 64;
            if (t + 1 < ntiles) {
                stage(t + 1, bi ^ 1);                       // prefetch next tile
                asm volatile("s_waitcnt vmcnt(8)" ::: "memory");  // tile t landed
            } else {
                asm volatile("s_waitcnt vmcnt(0)" ::: "memory");
            }
            __builtin_amdgcn_s_barrier();

            const char* Kb = (const char*)(&Klds[bi][0]);
            const char* Vb = (const char*)(&Vlds[bi][0]);

            // ---- S^T = K Q^T (swapped operands); q pre-scaled ----
            f32x4 st[4];
#pragma unroll
            for (int nf = 0; nf < 4; ++nf) st[nf] = (f32x4){0.f,0.f,0.f,0.f};
            __builtin_amdgcn_s_setprio(1);
#pragma unroll
            for (int nf = 0; nf < 4; ++nf) {
                int row = nf * 16 + l16;                    // key row
#pragma unroll
                for (int kd = 0; kd < 4; ++kd) {
                    bf16x8 kf = *reinterpret_cast<const bf16x8*>(
                        Kb + row * 256 + ((kd * 64 + lg * 16) ^ ((row & 7) << 4)));
                    st[nf] = __builtin_amdgcn_mfma_f32_16x16x32_bf16(
                        kf, qfrag[kd], st[nf], 0, 0, 0);
                }
            }
            __builtin_amdgcn_s_setprio(0);

            // ---- softmax (exp2 direct, no max), pack P -> LDS ----
            const bool diag = (t == ntiles - 1);
            {
                float lacc = 0.f;
                const int q = qt * 16 + l16;
#pragma unroll
                for (int nf = 0; nf < 4; ++nf) {
                    float cs0 = st[nf][0];
                    float cs1 = st[nf][1];
                    float cs2 = st[nf][2];
                    float cs3 = st[nf][3];
                    if (diag) {
                        const int keyb = k0 + nf * 16 + lg * 4;
                        if (keyb + 0 > q) cs0 = -INFINITY;
                        if (keyb + 1 > q) cs1 = -INFINITY;
                        if (keyb + 2 > q) cs2 = -INFINITY;
                        if (keyb + 3 > q) cs3 = -INFINITY;
                    }
                    float p0 = exp2f(cs0), p1 = exp2f(cs1);
                    float p2 = exp2f(cs2), p3 = exp2f(cs3);
                    lacc += (p0 + p1) + (p2 + p3);
                    uint2 pk = { cvtpk_bf16(p0, p1), cvtpk_bf16(p2, p3) };
                    *reinterpret_cast<uint2*>(
                        &Pl[w][l16][(nf * 16 + lg * 4) ^ pswz]) = pk;
                }
                lacc += __shfl_xor(lacc, 16, 64);
                lacc += __shfl_xor(lacc, 32, 64);
                lsum += lacc;
            }

            // ---- ctx^T += V^T P^T ----
            __builtin_amdgcn_s_setprio(1);
#pragma unroll
            for (int kc = 0; kc < 2; ++kc) {
                bf16x8 pf = *reinterpret_cast<const bf16x8*>(
                    &Pl[w][l16][(kc * 32 + lg * 8) ^ pswz]);
#pragma unroll
                for (int nd = 0; nd < 8; ++nd) {
                    int row = nd * 16 + l16;                // d row of V^T
                    bf16x8 vf = *reinterpret_cast<const bf16x8*>(
                        Vb + row * 128 + ((kc * 64 + lg * 16) ^ ((row & 7) << 4)));
                    acc[nd] = __builtin_amdgcn_mfma_f32_16x16x32_bf16(
                        vf, pf, acc[nd], 0, 0, 0);
                }
            }
            __builtin_amdgcn_s_setprio(0);
            __builtin_amdgcn_s_barrier();   // buf[bi] reads done before restage
        }

        // ---- epilogue: acc = ctx^T (col=q, row=d) ----
        {
            float inv = 1.0f / lsum;
            const int q = qt * 16 + l16;
#pragma unroll
            for (int nd = 0; nd < 8; ++nd) {
                bf16x4 o = { (short)f2bf(acc[nd][0] * inv),
                             (short)f2bf(acc[nd][1] * inv),
                             (short)f2bf(acc[nd][2] * inv),
                             (short)f2bf(acc[nd][3] * inv) };
                *reinterpret_cast<bf16x4*>(
                    &CTX[qbase + (size_t)q * 2048 + hh * 128 + nd * 16 + lg * 4]) = o;
            }
        }
    }
}

// ---------------------------------------------------------------------------
extern "C" void kernel_launch(void* const* d_in, const int* in_sizes, int n_in,
                              void* d_out, int out_size, void* d_ws, size_t ws_size,
                              hipStream_t stream)
{
    const float* x       = (const float*)d_in[0];
    const float* w_q     = (const float*)d_in[1];
    const float* w_kv    = (const float*)d_in[2];
    const float* w_dense = (const float*)d_in[3];

    const int M = 4096;                            // B*SQ

    // ws (36 MB): kv 8 @0 | ctx 16 @8 | wqT 8 @24 (reused as wdT) | wkvT 4 @32
    char* ws = (char*)d_ws;
    unsigned short* kv_buf  = (unsigned short*)(ws);
    unsigned short* ctx_buf = (unsigned short*)(ws + (8u << 20));
    unsigned short* wqT     = (unsigned short*)(ws + (24u << 20));
    unsigned short* wkvT    = (unsigned short*)(ws + (32u << 20));
    unsigned short* wdT     = wqT;
    // d_out (32 MB): xbf [0:16M] (dead after qkv GEMM) | q_buf [16:32M];
    // vt [0:4M] reuses xbf's region; dense GEMM finally overwrites all of d_out.
    unsigned short* xbf    = (unsigned short*)d_out;
    unsigned short* q_buf  = (unsigned short*)d_out + (size_t)M * 2048;
    unsigned short* vt_buf = (unsigned short*)d_out;

    dim3 blk(256);
    prep1_kernel<<<dim3(5632), blk, 0, stream>>>(x, xbf, w_q, wqT, w_kv, wkvT);
    // qkv: 128x192 tiles, grid 16 n-tiles x 32 m-tiles = 512 blocks (2/CU)
    gemm_qkv_kernel<<<dim3(16, 32), blk, 0, stream>>>(
        xbf, wqT, (void*)q_buf, (void*)kv_buf, M, 3072, 2048);
    prep2_kernel<<<dim3(1280), blk, 0, stream>>>(w_dense, wdT, kv_buf, vt_buf);
    attn_kernel<<<dim3(512), blk, 0, stream>>>(q_buf, kv_buf, vt_buf, ctx_buf);
    gemm_dense_kernel<<<dim3(16, 32), blk, 0, stream>>>(
        ctx_buf, wdT, (float*)d_out, M, 2048, 2048);
}

// Round 24
// 171.533 us; speedup vs baseline: 1.1117x; 1.0047x over previous
//
#include <hip/hip_runtime.h>
#include <hip/hip_bf16.h>

// ---------------------------------------------------------------------------
// Fused GQA attention block: out = dense( attn( x*Wq, x*Wkv ) )
// B=2, SQ=2048, HIDDEN=2048, HEADS=16, GROUPS=4, KVC=128, causal, scale=1/sqrt(128)
// R24: V-transpose fused into qkv epilogue (v cols written transposed to vt
//      directly; vtrans kernel deleted; kv_buf holds K only).  vt moves to
//      ws+36MB.  Rest (attn v10, dense, qkv loop, prep1) frozen from R23.
// ---------------------------------------------------------------------------

typedef __attribute__((ext_vector_type(4))) float f32x4;
typedef __attribute__((ext_vector_type(8))) short bf16x8;
typedef __attribute__((ext_vector_type(4))) short bf16x4;

__device__ __forceinline__ unsigned short f2bf(float f) {
    unsigned u = __builtin_bit_cast(unsigned, f);
    unsigned r = u + 0x7fffu + ((u >> 16) & 1u);   // round-to-nearest-even
    return (unsigned short)(r >> 16);
}

__device__ __forceinline__ unsigned cvtpk_bf16(float lo, float hi) {
    unsigned r;
    asm("v_cvt_pk_bf16_f32 %0, %1, %2" : "=v"(r) : "v"(lo), "v"(hi));
    return r;
}

// async global->LDS, 16B/lane; LDS dest = wave-uniform base + lane*16
__device__ __forceinline__ void gl_lds16(const void* g, void* l) {
    __builtin_amdgcn_global_load_lds(
        (const __attribute__((address_space(1))) unsigned int*)g,
        (__attribute__((address_space(3))) unsigned int*)l, 16, 0, 0);
}

// XCD-aware bijective remap (requires nwg % 8 == 0)
__device__ __forceinline__ int xcd_swizzle(int lin, int nwg) {
    return (lin & 7) * (nwg >> 3) + (lin >> 3);
}

// ---------------------------------------------------------------------------
// Fused prep bodies
// ---------------------------------------------------------------------------
__device__ __forceinline__ void xcvt_body(const float* __restrict__ in,
                                          unsigned short* __restrict__ out,
                                          int blk)
{
    size_t i = ((size_t)blk * 256 + threadIdx.x) * 8;
    float4 a = *reinterpret_cast<const float4*>(&in[i]);
    float4 b = *reinterpret_cast<const float4*>(&in[i + 4]);
    bf16x8 o = { (short)f2bf(a.x), (short)f2bf(a.y),
                 (short)f2bf(a.z), (short)f2bf(a.w),
                 (short)f2bf(b.x), (short)f2bf(b.y),
                 (short)f2bf(b.z), (short)f2bf(b.w) };
    *reinterpret_cast<bf16x8*>(&out[i]) = o;
}

// fp32 [K][N] -> bf16 [N][K], one 64x64 tile; T is 64x72 shared scratch
__device__ __forceinline__ void wtrans_body(const float* __restrict__ in,
                                            unsigned short* __restrict__ out,
                                            int K, int N, int bx, int by,
                                            unsigned short* T)
{
    const int n0 = bx * 64, k0 = by * 64;
    const int tid = threadIdx.x;
#pragma unroll
    for (int i = 0; i < 4; ++i) {
        int f = tid + i * 256;
        int r = f >> 4;
        int c4 = (f & 15) * 4;
        float4 v = *reinterpret_cast<const float4*>(&in[(size_t)(k0 + r) * N + n0 + c4]);
        bf16x4 pk = { (short)f2bf(v.x), (short)f2bf(v.y),
                      (short)f2bf(v.z), (short)f2bf(v.w) };
        *reinterpret_cast<bf16x4*>(&T[r * 72 + c4]) = pk;
    }
    __syncthreads();
#pragma unroll
    for (int i = 0; i < 2; ++i) {
        int f = tid + i * 256;
        int nn = f >> 3;
        int s8 = (f & 7) * 8;
        bf16x8 o;
#pragma unroll
        for (int j = 0; j < 8; ++j) o[j] = T[(s8 + j) * 72 + nn];
        *reinterpret_cast<bf16x8*>(&out[(size_t)(n0 + nn) * K + k0 + s8]) = o;
    }
}

// prep1: xcvt (4096) | wtrans wq (1024) | wtrans wkv (512)  = 5632 blocks
__global__ __launch_bounds__(256)
void prep1_kernel(const float* __restrict__ x, unsigned short* __restrict__ xbf,
                  const float* __restrict__ w_q, unsigned short* __restrict__ wqT,
                  const float* __restrict__ w_kv, unsigned short* __restrict__ wkvT)
{
    __shared__ __align__(16) unsigned short T[64 * 72];
    const int bid = blockIdx.x;
    if (bid < 4096) {
        xcvt_body(x, xbf, bid);
    } else if (bid < 4096 + 1024) {
        int r = bid - 4096;
        wtrans_body(w_q, wqT, 2048, 2048, r & 31, r >> 5, T);
    } else {
        int r = bid - 5120;
        wtrans_body(w_kv, wkvT, 2048, 1024, r & 15, r >> 4, T);
    }
}

// prep2: wtrans wdense only (1024 blocks = exact 4/CU round)
__global__ __launch_bounds__(256)
void prep2_kernel(const float* __restrict__ w_dense, unsigned short* __restrict__ wdT)
{
    __shared__ __align__(16) unsigned short T[64 * 72];
    const int bid = blockIdx.x;
    wtrans_body(w_dense, wdT, 2048, 2048, bid & 31, bid >> 5, T);
}

// ---------------------------------------------------------------------------
// qkv GEMM (R23 structure): 128x192 tile, BK=64 dbuf, vmcnt(10), XCD swizzle.
// Grid 16x32 = 512 blocks = 2/CU exact fill; LDS = (16K A + 24K B) x 2 = 80KB.
// R24 epilogue routing:  col<2048 -> q (scaled);  2048<=col<2560 -> kv_buf K;
// col>=2560 -> vt TRANSPOSED (4 consecutive s rows per f32x4 = one bf16x4).
// ---------------------------------------------------------------------------
__global__ __launch_bounds__(256)
void gemm_qkv_kernel(const unsigned short* __restrict__ A,
                     const unsigned short* __restrict__ BT,
                     void* __restrict__ C0v, void* __restrict__ C1v,
                     unsigned short* __restrict__ VT,
                     int M, int N, int K)
{
    __shared__ __align__(16) unsigned short Alds[2][128 * 64];   // 2 x 16KB
    __shared__ __align__(16) unsigned short Blds[2][192 * 64];   // 2 x 24KB

    const int tid = threadIdx.x;
    const int lane = tid & 63;
    const int wid = tid >> 6;
    const int wr = wid >> 1, wc = wid & 1;
    const int nbx = gridDim.x;                  // 16 n-tiles of 192
    const int lin = blockIdx.y * nbx + blockIdx.x;
    const int sl = xcd_swizzle(lin, nbx * gridDim.y);
    const int m0 = (sl / nbx) * 128;
    const int n0 = (sl % nbx) * 192;
    const int l16 = lane & 15, lg = lane >> 4;

    f32x4 acc[4][6];
#pragma unroll
    for (int m = 0; m < 4; ++m)
#pragma unroll
        for (int n = 0; n < 6; ++n) acc[m][n] = (f32x4){0.f, 0.f, 0.f, 0.f};

    // stage one BK=64 tile: A 128x64 (4 issues) + B 192x64 (6 issues)
    auto stage = [&](int kt, int bi) {
#pragma unroll
        for (int i = 0; i < 4; ++i) {
            int row = i * 32 + (tid >> 3);
            int cb = ((tid & 7) * 16) ^ ((row & 7) << 4);
            gl_lds16((const char*)A + ((size_t)(m0 + row) * K + kt) * 2 + cb,
                     (char*)(&Alds[bi][0]) + i * 4096 + wid * 1024);
        }
#pragma unroll
        for (int i = 0; i < 6; ++i) {
            int row = i * 32 + (tid >> 3);
            int cb = ((tid & 7) * 16) ^ ((row & 7) << 4);
            gl_lds16((const char*)BT + ((size_t)(n0 + row) * K + kt) * 2 + cb,
                     (char*)(&Blds[bi][0]) + i * 4096 + wid * 1024);
        }
    };

    const int NK = K / 64;
    stage(0, 0);
    int cur = 0;

    for (int kti = 0; kti < NK; ++kti) {
        if (kti + 1 < NK) {
            stage((kti + 1) * 64, cur ^ 1);
            asm volatile("s_waitcnt vmcnt(10)" ::: "memory");  // tile kti landed
        } else {
            asm volatile("s_waitcnt vmcnt(0)" ::: "memory");
        }
        __builtin_amdgcn_s_barrier();

        const char* Ab = (const char*)(&Alds[cur][0]);
        const char* Bb = (const char*)(&Blds[cur][0]);

        bf16x8 af[2][4], bf[2][6];
#pragma unroll
        for (int kd = 0; kd < 2; ++kd) {
#pragma unroll
            for (int m = 0; m < 4; ++m) {
                int row = wr * 64 + m * 16 + l16;
                af[kd][m] = *reinterpret_cast<const bf16x8*>(
                    Ab + row * 128 + ((kd * 64 + lg * 16) ^ ((row & 7) << 4)));
            }
#pragma unroll
            for (int n = 0; n < 6; ++n) {
                int row = wc * 96 + n * 16 + l16;
                bf[kd][n] = *reinterpret_cast<const bf16x8*>(
                    Bb + row * 128 + ((kd * 64 + lg * 16) ^ ((row & 7) << 4)));
            }
        }
#pragma unroll
        for (int kd = 0; kd < 2; ++kd)
#pragma unroll
            for (int m = 0; m < 4; ++m)
#pragma unroll
                for (int n = 0; n < 6; ++n)
                    acc[m][n] = __builtin_amdgcn_mfma_f32_16x16x32_bf16(
                        af[kd][m], bf[kd][n], acc[m][n], 0, 0, 0);

        __builtin_amdgcn_s_barrier();
        cur ^= 1;
    }

    // ---- epilogue: per-column q / K / V-transposed routing ----
#pragma unroll
    for (int m = 0; m < 4; ++m) {
#pragma unroll
        for (int n = 0; n < 6; ++n) {
            int row0 = m0 + wr * 64 + m * 16 + lg * 4;      // 4 consecutive rows
            int col = n0 + wc * 96 + n * 16 + l16;
            if (col < 2048) {            // q: fold scale * log2(e)
#pragma unroll
                for (int r = 0; r < 4; ++r)
                    ((unsigned short*)C0v)[(size_t)(row0 + r) * 2048 + col] =
                        f2bf(acc[m][n][r] * 0.12751879523209208f);
            } else if (col < 2560) {     // K -> kv_buf
#pragma unroll
                for (int r = 0; r < 4; ++r)
                    ((unsigned short*)C1v)[(size_t)(row0 + r) * 1024 + (col - 2048)] =
                        f2bf(acc[m][n][r]);
            } else {                     // V -> vt transposed: [b*512+vd][s]
                int vd = col - 2560;                         // 0..511
                int b = row0 >> 11;
                int s = row0 & 2047;                         // s..s+3 contiguous
                bf16x4 o = { (short)f2bf(acc[m][n][0]), (short)f2bf(acc[m][n][1]),
                             (short)f2bf(acc[m][n][2]), (short)f2bf(acc[m][n][3]) };
                *reinterpret_cast<bf16x4*>(
                    &VT[(size_t)(b * 512 + vd) * 2048 + s]) = o;
            }
        }
    }
}

// ---------------------------------------------------------------------------
// Dense GEMM: BK=64 dbuf + XCD swizzle.  fp32 out.  (frozen R23)
// ---------------------------------------------------------------------------
__global__ __launch_bounds__(256)
void gemm_dense_kernel(const unsigned short* __restrict__ A,
                       const unsigned short* __restrict__ BT,
                       float* __restrict__ C, int M, int N, int K)
{
    __shared__ __align__(16) unsigned short Alds[2][128 * 64];
    __shared__ __align__(16) unsigned short Blds[2][128 * 64];

    const int tid = threadIdx.x;
    const int lane = tid & 63;
    const int wid = tid >> 6;
    const int wr = wid >> 1, wc = wid & 1;
    const int nbx = gridDim.x;
    const int lin = blockIdx.y * nbx + blockIdx.x;
    const int sl = xcd_swizzle(lin, nbx * gridDim.y);
    const int m0 = (sl / nbx) * 128;
    const int n0 = (sl % nbx) * 128;
    const int l16 = lane & 15, lg = lane >> 4;

    f32x4 acc[4][4];
#pragma unroll
    for (int m = 0; m < 4; ++m)
#pragma unroll
        for (int n = 0; n < 4; ++n) acc[m][n] = (f32x4){0.f, 0.f, 0.f, 0.f};

    auto stage = [&](int kt, int bi) {
#pragma unroll
        for (int i = 0; i < 4; ++i) {
            int row = i * 32 + (tid >> 3);
            int cb = ((tid & 7) * 16) ^ ((row & 7) << 4);
            gl_lds16((const char*)A + ((size_t)(m0 + row) * K + kt) * 2 + cb,
                     (char*)(&Alds[bi][0]) + i * 4096 + wid * 1024);
            gl_lds16((const char*)BT + ((size_t)(n0 + row) * K + kt) * 2 + cb,
                     (char*)(&Blds[bi][0]) + i * 4096 + wid * 1024);
        }
    };

    const int NK = K / 64;
    stage(0, 0);
    int cur = 0;

    for (int kti = 0; kti < NK; ++kti) {
        if (kti + 1 < NK) {
            stage((kti + 1) * 64, cur ^ 1);
            asm volatile("s_waitcnt vmcnt(8)" ::: "memory");
        } else {
            asm volatile("s_waitcnt vmcnt(0)" ::: "memory");
        }
        __builtin_amdgcn_s_barrier();

        const char* Ab = (const char*)(&Alds[cur][0]);
        const char* Bb = (const char*)(&Blds[cur][0]);

        bf16x8 af[2][4], bf[2][4];
#pragma unroll
        for (int kd = 0; kd < 2; ++kd) {
#pragma unroll
            for (int m = 0; m < 4; ++m) {
                int row = wr * 64 + m * 16 + l16;
                af[kd][m] = *reinterpret_cast<const bf16x8*>(
                    Ab + row * 128 + ((kd * 64 + lg * 16) ^ ((row & 7) << 4)));
            }
#pragma unroll
            for (int n = 0; n < 4; ++n) {
                int row = wc * 64 + n * 16 + l16;
                bf[kd][n] = *reinterpret_cast<const bf16x8*>(
                    Bb + row * 128 + ((kd * 64 + lg * 16) ^ ((row & 7) << 4)));
            }
        }
#pragma unroll
        for (int kd = 0; kd < 2; ++kd)
#pragma unroll
            for (int m = 0; m < 4; ++m)
#pragma unroll
                for (int n = 0; n < 4; ++n)
                    acc[m][n] = __builtin_amdgcn_mfma_f32_16x16x32_bf16(
                        af[kd][m], bf[kd][n], acc[m][n], 0, 0, 0);

        __builtin_amdgcn_s_barrier();
        cur ^= 1;
    }

#pragma unroll
    for (int m = 0; m < 4; ++m) {
#pragma unroll
        for (int n = 0; n < 4; ++n) {
#pragma unroll
            for (int r = 0; r < 4; ++r) {
                int row = m0 + wr * 64 + m * 16 + lg * 4 + r;
                int col = n0 + wc * 64 + n * 16 + l16;
                C[(size_t)row * N + col] = acc[m][n][r];
            }
        }
    }
}

// ---------------------------------------------------------------------------
// Flash attention v10 (best measured 72.4us): 16-row q-tiles; block (gb, pi)
// serially processes q-tile 127-pi then pi -> uniform 33 phases/block,
// 512 blocks = 2/CU.  K/V double-buffered, counted vmcnt(8); 72KB LDS.
// Swapped S^T, exp2-direct softmax (scale pre-folded), swizzled P.
// ---------------------------------------------------------------------------
__global__ __launch_bounds__(256)
void attn_kernel(const unsigned short* __restrict__ Q,   // [b][s][h*128+d] (q pre-scaled)
                 const unsigned short* __restrict__ KV,  // [b][s][1024] (k at g*128)
                 const unsigned short* __restrict__ VT,  // [b*4+g][d][s]
                 unsigned short* __restrict__ CTX)       // [b][s][h*128+d]
{
    constexpr int SQ = 2048;
    __shared__ __align__(16) unsigned short Klds[2][64 * 128];   // 32KB
    __shared__ __align__(16) unsigned short Vlds[2][128 * 64];   // 32KB
    __shared__ __align__(16) unsigned short Pl[4][16][64];       //  8KB

    const int tid = threadIdx.x;
    const int lane = tid & 63;
    const int w = tid >> 6;                     // 0..3 = head within group
    const int l16 = lane & 15, lg = lane >> 4;

    const int bid = blockIdx.x;
    const int gb = bid & 7;                     // XCD pin
    const int g = gb & 3, b = gb >> 2;
    const int pi = bid >> 3;                    // 0..63 pair index
    const int hh = g * 4 + w;

    const size_t qbase = (size_t)b * SQ * 2048;
    const char* KVb = (const char*)KV + (size_t)b * SQ * 2048;  // bytes
    const char* VTb = (const char*)VT;

    const int pswz = (l16 & 7) << 3;            // P key-swizzle for this lane

    auto stage = [&](int t, int bi) {
        const int k0 = t * 64;
#pragma unroll
        for (int i = 0; i < 4; ++i) {
            int row = w * 16 + i * 4 + (lane >> 4);
            int scol = ((lane & 15) * 16) ^ ((row & 7) << 4);
            gl_lds16(KVb + (size_t)(k0 + row) * 2048 + g * 256 + scol,
                     (char*)(&Klds[bi][0]) + w * 4096 + i * 1024);
        }
#pragma unroll
        for (int i = 0; i < 4; ++i) {
            int row = w * 32 + i * 8 + (lane >> 3);
            int scol = ((lane & 7) * 16) ^ ((row & 7) << 4);
            gl_lds16(VTb + ((size_t)(gb * 128 + row) * 2048 + k0) * 2 + scol,
                     (char*)(&Vlds[bi][0]) + w * 4096 + i * 1024);
        }
    };

#pragma unroll 1
    for (int seg = 0; seg < 2; ++seg) {
        const int qt = seg ? pi : (127 - pi);   // long tile first
        const int ntiles = qt / 4 + 1;

        bf16x8 qfrag[4];
#pragma unroll
        for (int kd = 0; kd < 4; ++kd)
            qfrag[kd] = *reinterpret_cast<const bf16x8*>(
                &Q[qbase + (size_t)(qt * 16 + l16) * 2048 + hh * 128 + kd * 32 + lg * 8]);

        float lsum = 0.f;
        f32x4 acc[8];
#pragma unroll
        for (int nd = 0; nd < 8; ++nd) acc[nd] = (f32x4){0.f,0.f,0.f,0.f};

        stage(0, 0);

        for (int t = 0; t < ntiles; ++t) {
            const int bi = t & 1;
            const int k0 = t * 64;
            if (t + 1 < ntiles) {
                stage(t + 1, bi ^ 1);                       // prefetch next tile
                asm volatile("s_waitcnt vmcnt(8)" ::: "memory");  // tile t landed
            } else {
                asm volatile("s_waitcnt vmcnt(0)" ::: "memory");
            }
            __builtin_amdgcn_s_barrier();

            const char* Kb = (const char*)(&Klds[bi][0]);
            const char* Vb = (const char*)(&Vlds[bi][0]);

            // ---- S^T = K Q^T (swapped operands); q pre-scaled ----
            f32x4 st[4];
#pragma unroll
            for (int nf = 0; nf < 4; ++nf) st[nf] = (f32x4){0.f,0.f,0.f,0.f};
            __builtin_amdgcn_s_setprio(1);
#pragma unroll
            for (int nf = 0; nf < 4; ++nf) {
                int row = nf * 16 + l16;                    // key row
#pragma unroll
                for (int kd = 0; kd < 4; ++kd) {
                    bf16x8 kf = *reinterpret_cast<const bf16x8*>(
                        Kb + row * 256 + ((kd * 64 + lg * 16) ^ ((row & 7) << 4)));
                    st[nf] = __builtin_amdgcn_mfma_f32_16x16x32_bf16(
                        kf, qfrag[kd], st[nf], 0, 0, 0);
                }
            }
            __builtin_amdgcn_s_setprio(0);

            // ---- softmax (exp2 direct, no max), pack P -> LDS ----
            const bool diag = (t == ntiles - 1);
            {
                float lacc = 0.f;
                const int q = qt * 16 + l16;
#pragma unroll
                for (int nf = 0; nf < 4; ++nf) {
                    float cs0 = st[nf][0];
                    float cs1 = st[nf][1];
                    float cs2 = st[nf][2];
                    float cs3 = st[nf][3];
                    if (diag) {
                        const int keyb = k0 + nf * 16 + lg * 4;
                        if (keyb + 0 > q) cs0 = -INFINITY;
                        if (keyb + 1 > q) cs1 = -INFINITY;
                        if (keyb + 2 > q) cs2 = -INFINITY;
                        if (keyb + 3 > q) cs3 = -INFINITY;
                    }
                    float p0 = exp2f(cs0), p1 = exp2f(cs1);
                    float p2 = exp2f(cs2), p3 = exp2f(cs3);
                    lacc += (p0 + p1) + (p2 + p3);
                    uint2 pk = { cvtpk_bf16(p0, p1), cvtpk_bf16(p2, p3) };
                    *reinterpret_cast<uint2*>(
                        &Pl[w][l16][(nf * 16 + lg * 4) ^ pswz]) = pk;
                }
                lacc += __shfl_xor(lacc, 16, 64);
                lacc += __shfl_xor(lacc, 32, 64);
                lsum += lacc;
            }

            // ---- ctx^T += V^T P^T ----
            __builtin_amdgcn_s_setprio(1);
#pragma unroll
            for (int kc = 0; kc < 2; ++kc) {
                bf16x8 pf = *reinterpret_cast<const bf16x8*>(
                    &Pl[w][l16][(kc * 32 + lg * 8) ^ pswz]);
#pragma unroll
                for (int nd = 0; nd < 8; ++nd) {
                    int row = nd * 16 + l16;                // d row of V^T
                    bf16x8 vf = *reinterpret_cast<const bf16x8*>(
                        Vb + row * 128 + ((kc * 64 + lg * 16) ^ ((row & 7) << 4)));
                    acc[nd] = __builtin_amdgcn_mfma_f32_16x16x32_bf16(
                        vf, pf, acc[nd], 0, 0, 0);
                }
            }
            __builtin_amdgcn_s_setprio(0);
            __builtin_amdgcn_s_barrier();   // buf[bi] reads done before restage
        }

        // ---- epilogue: acc = ctx^T (col=q, row=d) ----
        {
            float inv = 1.0f / lsum;
            const int q = qt * 16 + l16;
#pragma unroll
            for (int nd = 0; nd < 8; ++nd) {
                bf16x4 o = { (short)f2bf(acc[nd][0] * inv),
                             (short)f2bf(acc[nd][1] * inv),
                             (short)f2bf(acc[nd][2] * inv),
                             (short)f2bf(acc[nd][3] * inv) };
                *reinterpret_cast<bf16x4*>(
                    &CTX[qbase + (size_t)q * 2048 + hh * 128 + nd * 16 + lg * 4]) = o;
            }
        }
    }
}

// ---------------------------------------------------------------------------
extern "C" void kernel_launch(void* const* d_in, const int* in_sizes, int n_in,
                              void* d_out, int out_size, void* d_ws, size_t ws_size,
                              hipStream_t stream)
{
    const float* x       = (const float*)d_in[0];
    const float* w_q     = (const float*)d_in[1];
    const float* w_kv    = (const float*)d_in[2];
    const float* w_dense = (const float*)d_in[3];

    const int M = 4096;                            // B*SQ

    // ws (40 MB, proven R1-R4): kv 8 @0 | ctx 16 @8 | wqT 8 @24 (reused as
    // wdT) | wkvT 4 @32 | vt 4 @36
    char* ws = (char*)d_ws;
    unsigned short* kv_buf  = (unsigned short*)(ws);
    unsigned short* ctx_buf = (unsigned short*)(ws + (8u << 20));
    unsigned short* wqT     = (unsigned short*)(ws + (24u << 20));
    unsigned short* wkvT    = (unsigned short*)(ws + (32u << 20));
    unsigned short* wdT     = wqT;
    unsigned short* vt_buf  = (unsigned short*)(ws + (36u << 20));
    // d_out (32 MB): xbf [0:16M] (dead after qkv GEMM) | q_buf [16:32M];
    // dense GEMM finally overwrites all of d_out.
    unsigned short* xbf    = (unsigned short*)d_out;
    unsigned short* q_buf  = (unsigned short*)d_out + (size_t)M * 2048;

    dim3 blk(256);
    prep1_kernel<<<dim3(5632), blk, 0, stream>>>(x, xbf, w_q, wqT, w_kv, wkvT);
    // qkv: 128x192 tiles, 512 blocks (2/CU); writes q, K, and V-transposed
    gemm_qkv_kernel<<<dim3(16, 32), blk, 0, stream>>>(
        xbf, wqT, (void*)q_buf, (void*)kv_buf, vt_buf, M, 3072, 2048);
    // prep2: wdense transpose only (overwrites wqT region after qkv reads it)
    prep2_kernel<<<dim3(1024), blk, 0, stream>>>(w_dense, wdT);
    attn_kernel<<<dim3(512), blk, 0, stream>>>(q_buf, kv_buf, vt_buf, ctx_buf);
    gemm_dense_kernel<<<dim3(16, 32), blk, 0, stream>>>(
        ctx_buf, wdT, (float*)d_out, M, 2048, 2048);
}

// Round 25
// 166.598 us; speedup vs baseline: 1.1446x; 1.0296x over previous
//
#include <hip/hip_runtime.h>
#include <hip/hip_bf16.h>

// ---------------------------------------------------------------------------
// Fused GQA attention block: out = dense( attn( x*Wq, x*Wkv ) )
// B=2, SQ=2048, HIDDEN=2048, HEADS=16, GROUPS=4, KVC=128, causal, scale=1/sqrt(128)
// R25: prep2 (w_dense transpose) folded into the attn dispatch as extra
//      blocks (bids >= 512); its work hides in attn's retirement jitter and
//      one launch boundary disappears.  attn path byte-identical to v10.
//      qkv/dense GEMMs, prep1, layout frozen from R24.
// ---------------------------------------------------------------------------

typedef __attribute__((ext_vector_type(4))) float f32x4;
typedef __attribute__((ext_vector_type(8))) short bf16x8;
typedef __attribute__((ext_vector_type(4))) short bf16x4;

__device__ __forceinline__ unsigned short f2bf(float f) {
    unsigned u = __builtin_bit_cast(unsigned, f);
    unsigned r = u + 0x7fffu + ((u >> 16) & 1u);   // round-to-nearest-even
    return (unsigned short)(r >> 16);
}

__device__ __forceinline__ unsigned cvtpk_bf16(float lo, float hi) {
    unsigned r;
    asm("v_cvt_pk_bf16_f32 %0, %1, %2" : "=v"(r) : "v"(lo), "v"(hi));
    return r;
}

// async global->LDS, 16B/lane; LDS dest = wave-uniform base + lane*16
__device__ __forceinline__ void gl_lds16(const void* g, void* l) {
    __builtin_amdgcn_global_load_lds(
        (const __attribute__((address_space(1))) unsigned int*)g,
        (__attribute__((address_space(3))) unsigned int*)l, 16, 0, 0);
}

// XCD-aware bijective remap (requires nwg % 8 == 0)
__device__ __forceinline__ int xcd_swizzle(int lin, int nwg) {
    return (lin & 7) * (nwg >> 3) + (lin >> 3);
}

// ---------------------------------------------------------------------------
// Fused prep bodies
// ---------------------------------------------------------------------------
__device__ __forceinline__ void xcvt_body(const float* __restrict__ in,
                                          unsigned short* __restrict__ out,
                                          int blk)
{
    size_t i = ((size_t)blk * 256 + threadIdx.x) * 8;
    float4 a = *reinterpret_cast<const float4*>(&in[i]);
    float4 b = *reinterpret_cast<const float4*>(&in[i + 4]);
    bf16x8 o = { (short)f2bf(a.x), (short)f2bf(a.y),
                 (short)f2bf(a.z), (short)f2bf(a.w),
                 (short)f2bf(b.x), (short)f2bf(b.y),
                 (short)f2bf(b.z), (short)f2bf(b.w) };
    *reinterpret_cast<bf16x8*>(&out[i]) = o;
}

// fp32 [K][N] -> bf16 [N][K], one 64x64 tile; T is 64x72 shared scratch
__device__ __forceinline__ void wtrans_body(const float* __restrict__ in,
                                            unsigned short* __restrict__ out,
                                            int K, int N, int bx, int by,
                                            unsigned short* T)
{
    const int n0 = bx * 64, k0 = by * 64;
    const int tid = threadIdx.x;
#pragma unroll
    for (int i = 0; i < 4; ++i) {
        int f = tid + i * 256;
        int r = f >> 4;
        int c4 = (f & 15) * 4;
        float4 v = *reinterpret_cast<const float4*>(&in[(size_t)(k0 + r) * N + n0 + c4]);
        bf16x4 pk = { (short)f2bf(v.x), (short)f2bf(v.y),
                      (short)f2bf(v.z), (short)f2bf(v.w) };
        *reinterpret_cast<bf16x4*>(&T[r * 72 + c4]) = pk;
    }
    __syncthreads();
#pragma unroll
    for (int i = 0; i < 2; ++i) {
        int f = tid + i * 256;
        int nn = f >> 3;
        int s8 = (f & 7) * 8;
        bf16x8 o;
#pragma unroll
        for (int j = 0; j < 8; ++j) o[j] = T[(s8 + j) * 72 + nn];
        *reinterpret_cast<bf16x8*>(&out[(size_t)(n0 + nn) * K + k0 + s8]) = o;
    }
}

// prep1: xcvt (4096) | wtrans wq (1024) | wtrans wkv (512)  = 5632 blocks
__global__ __launch_bounds__(256)
void prep1_kernel(const float* __restrict__ x, unsigned short* __restrict__ xbf,
                  const float* __restrict__ w_q, unsigned short* __restrict__ wqT,
                  const float* __restrict__ w_kv, unsigned short* __restrict__ wkvT)
{
    __shared__ __align__(16) unsigned short T[64 * 72];
    const int bid = blockIdx.x;
    if (bid < 4096) {
        xcvt_body(x, xbf, bid);
    } else if (bid < 4096 + 1024) {
        int r = bid - 4096;
        wtrans_body(w_q, wqT, 2048, 2048, r & 31, r >> 5, T);
    } else {
        int r = bid - 5120;
        wtrans_body(w_kv, wkvT, 2048, 1024, r & 15, r >> 4, T);
    }
}

// ---------------------------------------------------------------------------
// qkv GEMM (R23 structure): 128x192 tile, BK=64 dbuf, vmcnt(10), XCD swizzle.
// Grid 16x32 = 512 blocks = 2/CU exact fill; LDS = (16K A + 24K B) x 2 = 80KB.
// Epilogue routing: col<2048 -> q (scaled); 2048<=col<2560 -> kv_buf K;
// col>=2560 -> vt TRANSPOSED (4 consecutive s rows per f32x4 = one bf16x4).
// ---------------------------------------------------------------------------
__global__ __launch_bounds__(256)
void gemm_qkv_kernel(const unsigned short* __restrict__ A,
                     const unsigned short* __restrict__ BT,
                     void* __restrict__ C0v, void* __restrict__ C1v,
                     unsigned short* __restrict__ VT,
                     int M, int N, int K)
{
    __shared__ __align__(16) unsigned short Alds[2][128 * 64];   // 2 x 16KB
    __shared__ __align__(16) unsigned short Blds[2][192 * 64];   // 2 x 24KB

    const int tid = threadIdx.x;
    const int lane = tid & 63;
    const int wid = tid >> 6;
    const int wr = wid >> 1, wc = wid & 1;
    const int nbx = gridDim.x;                  // 16 n-tiles of 192
    const int lin = blockIdx.y * nbx + blockIdx.x;
    const int sl = xcd_swizzle(lin, nbx * gridDim.y);
    const int m0 = (sl / nbx) * 128;
    const int n0 = (sl % nbx) * 192;
    const int l16 = lane & 15, lg = lane >> 4;

    f32x4 acc[4][6];
#pragma unroll
    for (int m = 0; m < 4; ++m)
#pragma unroll
        for (int n = 0; n < 6; ++n) acc[m][n] = (f32x4){0.f, 0.f, 0.f, 0.f};

    auto stage = [&](int kt, int bi) {
#pragma unroll
        for (int i = 0; i < 4; ++i) {
            int row = i * 32 + (tid >> 3);
            int cb = ((tid & 7) * 16) ^ ((row & 7) << 4);
            gl_lds16((const char*)A + ((size_t)(m0 + row) * K + kt) * 2 + cb,
                     (char*)(&Alds[bi][0]) + i * 4096 + wid * 1024);
        }
#pragma unroll
        for (int i = 0; i < 6; ++i) {
            int row = i * 32 + (tid >> 3);
            int cb = ((tid & 7) * 16) ^ ((row & 7) << 4);
            gl_lds16((const char*)BT + ((size_t)(n0 + row) * K + kt) * 2 + cb,
                     (char*)(&Blds[bi][0]) + i * 4096 + wid * 1024);
        }
    };

    const int NK = K / 64;
    stage(0, 0);
    int cur = 0;

    for (int kti = 0; kti < NK; ++kti) {
        if (kti + 1 < NK) {
            stage((kti + 1) * 64, cur ^ 1);
            asm volatile("s_waitcnt vmcnt(10)" ::: "memory");  // tile kti landed
        } else {
            asm volatile("s_waitcnt vmcnt(0)" ::: "memory");
        }
        __builtin_amdgcn_s_barrier();

        const char* Ab = (const char*)(&Alds[cur][0]);
        const char* Bb = (const char*)(&Blds[cur][0]);

        bf16x8 af[2][4], bf[2][6];
#pragma unroll
        for (int kd = 0; kd < 2; ++kd) {
#pragma unroll
            for (int m = 0; m < 4; ++m) {
                int row = wr * 64 + m * 16 + l16;
                af[kd][m] = *reinterpret_cast<const bf16x8*>(
                    Ab + row * 128 + ((kd * 64 + lg * 16) ^ ((row & 7) << 4)));
            }
#pragma unroll
            for (int n = 0; n < 6; ++n) {
                int row = wc * 96 + n * 16 + l16;
                bf[kd][n] = *reinterpret_cast<const bf16x8*>(
                    Bb + row * 128 + ((kd * 64 + lg * 16) ^ ((row & 7) << 4)));
            }
        }
#pragma unroll
        for (int kd = 0; kd < 2; ++kd)
#pragma unroll
            for (int m = 0; m < 4; ++m)
#pragma unroll
                for (int n = 0; n < 6; ++n)
                    acc[m][n] = __builtin_amdgcn_mfma_f32_16x16x32_bf16(
                        af[kd][m], bf[kd][n], acc[m][n], 0, 0, 0);

        __builtin_amdgcn_s_barrier();
        cur ^= 1;
    }

    // ---- epilogue: per-column q / K / V-transposed routing ----
#pragma unroll
    for (int m = 0; m < 4; ++m) {
#pragma unroll
        for (int n = 0; n < 6; ++n) {
            int row0 = m0 + wr * 64 + m * 16 + lg * 4;      // 4 consecutive rows
            int col = n0 + wc * 96 + n * 16 + l16;
            if (col < 2048) {            // q: fold scale * log2(e)
#pragma unroll
                for (int r = 0; r < 4; ++r)
                    ((unsigned short*)C0v)[(size_t)(row0 + r) * 2048 + col] =
                        f2bf(acc[m][n][r] * 0.12751879523209208f);
            } else if (col < 2560) {     // K -> kv_buf
#pragma unroll
                for (int r = 0; r < 4; ++r)
                    ((unsigned short*)C1v)[(size_t)(row0 + r) * 1024 + (col - 2048)] =
                        f2bf(acc[m][n][r]);
            } else {                     // V -> vt transposed: [b*512+vd][s]
                int vd = col - 2560;                         // 0..511
                int b = row0 >> 11;
                int s = row0 & 2047;                         // s..s+3 contiguous
                bf16x4 o = { (short)f2bf(acc[m][n][0]), (short)f2bf(acc[m][n][1]),
                             (short)f2bf(acc[m][n][2]), (short)f2bf(acc[m][n][3]) };
                *reinterpret_cast<bf16x4*>(
                    &VT[(size_t)(b * 512 + vd) * 2048 + s]) = o;
            }
        }
    }
}

// ---------------------------------------------------------------------------
// Dense GEMM: BK=64 dbuf + XCD swizzle.  fp32 out.  (frozen R23)
// ---------------------------------------------------------------------------
__global__ __launch_bounds__(256)
void gemm_dense_kernel(const unsigned short* __restrict__ A,
                       const unsigned short* __restrict__ BT,
                       float* __restrict__ C, int M, int N, int K)
{
    __shared__ __align__(16) unsigned short Alds[2][128 * 64];
    __shared__ __align__(16) unsigned short Blds[2][128 * 64];

    const int tid = threadIdx.x;
    const int lane = tid & 63;
    const int wid = tid >> 6;
    const int wr = wid >> 1, wc = wid & 1;
    const int nbx = gridDim.x;
    const int lin = blockIdx.y * nbx + blockIdx.x;
    const int sl = xcd_swizzle(lin, nbx * gridDim.y);
    const int m0 = (sl / nbx) * 128;
    const int n0 = (sl % nbx) * 128;
    const int l16 = lane & 15, lg = lane >> 4;

    f32x4 acc[4][4];
#pragma unroll
    for (int m = 0; m < 4; ++m)
#pragma unroll
        for (int n = 0; n < 4; ++n) acc[m][n] = (f32x4){0.f, 0.f, 0.f, 0.f};

    auto stage = [&](int kt, int bi) {
#pragma unroll
        for (int i = 0; i < 4; ++i) {
            int row = i * 32 + (tid >> 3);
            int cb = ((tid & 7) * 16) ^ ((row & 7) << 4);
            gl_lds16((const char*)A + ((size_t)(m0 + row) * K + kt) * 2 + cb,
                     (char*)(&Alds[bi][0]) + i * 4096 + wid * 1024);
            gl_lds16((const char*)BT + ((size_t)(n0 + row) * K + kt) * 2 + cb,
                     (char*)(&Blds[bi][0]) + i * 4096 + wid * 1024);
        }
    };

    const int NK = K / 64;
    stage(0, 0);
    int cur = 0;

    for (int kti = 0; kti < NK; ++kti) {
        if (kti + 1 < NK) {
            stage((kti + 1) * 64, cur ^ 1);
            asm volatile("s_waitcnt vmcnt(8)" ::: "memory");
        } else {
            asm volatile("s_waitcnt vmcnt(0)" ::: "memory");
        }
        __builtin_amdgcn_s_barrier();

        const char* Ab = (const char*)(&Alds[cur][0]);
        const char* Bb = (const char*)(&Blds[cur][0]);

        bf16x8 af[2][4], bf[2][4];
#pragma unroll
        for (int kd = 0; kd < 2; ++kd) {
#pragma unroll
            for (int m = 0; m < 4; ++m) {
                int row = wr * 64 + m * 16 + l16;
                af[kd][m] = *reinterpret_cast<const bf16x8*>(
                    Ab + row * 128 + ((kd * 64 + lg * 16) ^ ((row & 7) << 4)));
            }
#pragma unroll
            for (int n = 0; n < 4; ++n) {
                int row = wc * 64 + n * 16 + l16;
                bf[kd][n] = *reinterpret_cast<const bf16x8*>(
                    Bb + row * 128 + ((kd * 64 + lg * 16) ^ ((row & 7) << 4)));
            }
        }
#pragma unroll
        for (int kd = 0; kd < 2; ++kd)
#pragma unroll
            for (int m = 0; m < 4; ++m)
#pragma unroll
                for (int n = 0; n < 4; ++n)
                    acc[m][n] = __builtin_amdgcn_mfma_f32_16x16x32_bf16(
                        af[kd][m], bf[kd][n], acc[m][n], 0, 0, 0);

        __builtin_amdgcn_s_barrier();
        cur ^= 1;
    }

#pragma unroll
    for (int m = 0; m < 4; ++m) {
#pragma unroll
        for (int n = 0; n < 4; ++n) {
#pragma unroll
            for (int r = 0; r < 4; ++r) {
                int row = m0 + wr * 64 + m * 16 + lg * 4 + r;
                int col = n0 + wc * 64 + n * 16 + l16;
                C[(size_t)row * N + col] = acc[m][n][r];
            }
        }
    }
}

// ---------------------------------------------------------------------------
// Fused attn (v10, bids 0..511, byte-identical math) + w_dense transpose
// (bids 512..1535, reusing Klds as scratch).  All blocks of one path only.
// ---------------------------------------------------------------------------
__global__ __launch_bounds__(256)
void attn_fused_kernel(const unsigned short* __restrict__ Q,   // pre-scaled q
                       const unsigned short* __restrict__ KV,  // K at g*128
                       const unsigned short* __restrict__ VT,  // [b*4+g][d][s]
                       unsigned short* __restrict__ CTX,
                       const float* __restrict__ w_dense,
                       unsigned short* __restrict__ wdT)
{
    constexpr int SQ = 2048;
    __shared__ __align__(16) unsigned short Klds[2][64 * 128];   // 32KB
    __shared__ __align__(16) unsigned short Vlds[2][128 * 64];   // 32KB
    __shared__ __align__(16) unsigned short Pl[4][16][64];       //  8KB

    const int bid = blockIdx.x;
    if (bid >= 512) {                   // ---- w_dense transpose path ----
        int r = bid - 512;              // 1024 tiles of 64x64
        wtrans_body(w_dense, wdT, 2048, 2048, r & 31, r >> 5,
                    (unsigned short*)&Klds[0][0]);
        return;
    }

    const int tid = threadIdx.x;
    const int lane = tid & 63;
    const int w = tid >> 6;                     // 0..3 = head within group
    const int l16 = lane & 15, lg = lane >> 4;

    const int gb = bid & 7;                     // XCD pin
    const int g = gb & 3, b = gb >> 2;
    const int pi = bid >> 3;                    // 0..63 pair index
    const int hh = g * 4 + w;

    const size_t qbase = (size_t)b * SQ * 2048;
    const char* KVb = (const char*)KV + (size_t)b * SQ * 2048;  // bytes
    const char* VTb = (const char*)VT;

    const int pswz = (l16 & 7) << 3;            // P key-swizzle for this lane

    auto stage = [&](int t, int bi) {
        const int k0 = t * 64;
#pragma unroll
        for (int i = 0; i < 4; ++i) {
            int row = w * 16 + i * 4 + (lane >> 4);
            int scol = ((lane & 15) * 16) ^ ((row & 7) << 4);
            gl_lds16(KVb + (size_t)(k0 + row) * 2048 + g * 256 + scol,
                     (char*)(&Klds[bi][0]) + w * 4096 + i * 1024);
        }
#pragma unroll
        for (int i = 0; i < 4; ++i) {
            int row = w * 32 + i * 8 + (lane >> 3);
            int scol = ((lane & 7) * 16) ^ ((row & 7) << 4);
            gl_lds16(VTb + ((size_t)(gb * 128 + row) * 2048 + k0) * 2 + scol,
                     (char*)(&Vlds[bi][0]) + w * 4096 + i * 1024);
        }
    };

#pragma unroll 1
    for (int seg = 0; seg < 2; ++seg) {
        const int qt = seg ? pi : (127 - pi);   // long tile first
        const int ntiles = qt / 4 + 1;

        bf16x8 qfrag[4];
#pragma unroll
        for (int kd = 0; kd < 4; ++kd)
            qfrag[kd] = *reinterpret_cast<const bf16x8*>(
                &Q[qbase + (size_t)(qt * 16 + l16) * 2048 + hh * 128 + kd * 32 + lg * 8]);

        float lsum = 0.f;
        f32x4 acc[8];
#pragma unroll
        for (int nd = 0; nd < 8; ++nd) acc[nd] = (f32x4){0.f,0.f,0.f,0.f};

        stage(0, 0);

        for (int t = 0; t < ntiles; ++t) {
            const int bi = t & 1;
            const int k0 = t * 64;
            if (t + 1 < ntiles) {
                stage(t + 1, bi ^ 1);                       // prefetch next tile
                asm volatile("s_waitcnt vmcnt(8)" ::: "memory");  // tile t landed
            } else {
                asm volatile("s_waitcnt vmcnt(0)" ::: "memory");
            }
            __builtin_amdgcn_s_barrier();

            const char* Kb = (const char*)(&Klds[bi][0]);
            const char* Vb = (const char*)(&Vlds[bi][0]);

            // ---- S^T = K Q^T (swapped operands); q pre-scaled ----
            f32x4 st[4];
#pragma unroll
            for (int nf = 0; nf < 4; ++nf) st[nf] = (f32x4){0.f,0.f,0.f,0.f};
            __builtin_amdgcn_s_setprio(1);
#pragma unroll
            for (int nf = 0; nf < 4; ++nf) {
                int row = nf * 16 + l16;                    // key row
#pragma unroll
                for (int kd = 0; kd < 4; ++kd) {
                    bf16x8 kf = *reinterpret_cast<const bf16x8*>(
                        Kb + row * 256 + ((kd * 64 + lg * 16) ^ ((row & 7) << 4)));
                    st[nf] = __builtin_amdgcn_mfma_f32_16x16x32_bf16(
                        kf, qfrag[kd], st[nf], 0, 0, 0);
                }
            }
            __builtin_amdgcn_s_setprio(0);

            // ---- softmax (exp2 direct, no max), pack P -> LDS ----
            const bool diag = (t == ntiles - 1);
            {
                float lacc = 0.f;
                const int q = qt * 16 + l16;
#pragma unroll
                for (int nf = 0; nf < 4; ++nf) {
                    float cs0 = st[nf][0];
                    float cs1 = st[nf][1];
                    float cs2 = st[nf][2];
                    float cs3 = st[nf][3];
                    if (diag) {
                        const int keyb = k0 + nf * 16 + lg * 4;
                        if (keyb + 0 > q) cs0 = -INFINITY;
                        if (keyb + 1 > q) cs1 = -INFINITY;
                        if (keyb + 2 > q) cs2 = -INFINITY;
                        if (keyb + 3 > q) cs3 = -INFINITY;
                    }
                    float p0 = exp2f(cs0), p1 = exp2f(cs1);
                    float p2 = exp2f(cs2), p3 = exp2f(cs3);
                    lacc += (p0 + p1) + (p2 + p3);
                    uint2 pk = { cvtpk_bf16(p0, p1), cvtpk_bf16(p2, p3) };
                    *reinterpret_cast<uint2*>(
                        &Pl[w][l16][(nf * 16 + lg * 4) ^ pswz]) = pk;
                }
                lacc += __shfl_xor(lacc, 16, 64);
                lacc += __shfl_xor(lacc, 32, 64);
                lsum += lacc;
            }

            // ---- ctx^T += V^T P^T ----
            __builtin_amdgcn_s_setprio(1);
#pragma unroll
            for (int kc = 0; kc < 2; ++kc) {
                bf16x8 pf = *reinterpret_cast<const bf16x8*>(
                    &Pl[w][l16][(kc * 32 + lg * 8) ^ pswz]);
#pragma unroll
                for (int nd = 0; nd < 8; ++nd) {
                    int row = nd * 16 + l16;                // d row of V^T
                    bf16x8 vf = *reinterpret_cast<const bf16x8*>(
                        Vb + row * 128 + ((kc * 64 + lg * 16) ^ ((row & 7) << 4)));
                    acc[nd] = __builtin_amdgcn_mfma_f32_16x16x32_bf16(
                        vf, pf, acc[nd], 0, 0, 0);
                }
            }
            __builtin_amdgcn_s_setprio(0);
            __builtin_amdgcn_s_barrier();   // buf[bi] reads done before restage
        }

        // ---- epilogue: acc = ctx^T (col=q, row=d) ----
        {
            float inv = 1.0f / lsum;
            const int q = qt * 16 + l16;
#pragma unroll
            for (int nd = 0; nd < 8; ++nd) {
                bf16x4 o = { (short)f2bf(acc[nd][0] * inv),
                             (short)f2bf(acc[nd][1] * inv),
                             (short)f2bf(acc[nd][2] * inv),
                             (short)f2bf(acc[nd][3] * inv) };
                *reinterpret_cast<bf16x4*>(
                    &CTX[qbase + (size_t)q * 2048 + hh * 128 + nd * 16 + lg * 4]) = o;
            }
        }
    }
}

// ---------------------------------------------------------------------------
extern "C" void kernel_launch(void* const* d_in, const int* in_sizes, int n_in,
                              void* d_out, int out_size, void* d_ws, size_t ws_size,
                              hipStream_t stream)
{
    const float* x       = (const float*)d_in[0];
    const float* w_q     = (const float*)d_in[1];
    const float* w_kv    = (const float*)d_in[2];
    const float* w_dense = (const float*)d_in[3];

    const int M = 4096;                            // B*SQ

    // ws (40 MB): kv 8 @0 | ctx 16 @8 | wqT 8 @24 (reused as wdT) | wkvT 4
    // @32 | vt 4 @36
    char* ws = (char*)d_ws;
    unsigned short* kv_buf  = (unsigned short*)(ws);
    unsigned short* ctx_buf = (unsigned short*)(ws + (8u << 20));
    unsigned short* wqT     = (unsigned short*)(ws + (24u << 20));
    unsigned short* wkvT    = (unsigned short*)(ws + (32u << 20));
    unsigned short* wdT     = wqT;
    unsigned short* vt_buf  = (unsigned short*)(ws + (36u << 20));
    // d_out (32 MB): xbf [0:16M] (dead after qkv GEMM) | q_buf [16:32M];
    // dense GEMM finally overwrites all of d_out.
    unsigned short* xbf    = (unsigned short*)d_out;
    unsigned short* q_buf  = (unsigned short*)d_out + (size_t)M * 2048;

    dim3 blk(256);
    prep1_kernel<<<dim3(5632), blk, 0, stream>>>(x, xbf, w_q, wqT, w_kv, wkvT);
    // qkv: 128x192 tiles, 512 blocks (2/CU); writes q, K, and V-transposed
    gemm_qkv_kernel<<<dim3(16, 32), blk, 0, stream>>>(
        xbf, wqT, (void*)q_buf, (void*)kv_buf, vt_buf, M, 3072, 2048);
    // attn (bids 0..511) + w_dense transpose (bids 512..1535) in one dispatch
    attn_fused_kernel<<<dim3(1536), blk, 0, stream>>>(
        q_buf, kv_buf, vt_buf, ctx_buf, w_dense, wdT);
    gemm_dense_kernel<<<dim3(16, 32), blk, 0, stream>>>(
        ctx_buf, wdT, (float*)d_out, M, 2048, 2048);
}